// Round 16
// baseline (222.435 us; speedup 1.0000x reference)
//
#include <hip/hip_runtime.h>

// ---------------------------------------------------------------------------
// Types / helpers
// ---------------------------------------------------------------------------
typedef __bf16 bf16x8 __attribute__((ext_vector_type(8)));
typedef float  f32x4  __attribute__((ext_vector_type(4)));

union U8 { bf16x8 v; __bf16 e[8]; unsigned short u[8]; };

// Native HW conversion (v_cvt_*_bf16), RNE.
__device__ __forceinline__ unsigned short f2bf(float f) {
  union { __bf16 b; unsigned short u; } c;
  c.b = (__bf16)f;
  return c.u;
}

__device__ __forceinline__ void async16(const void* g, void* l) {
  __builtin_amdgcn_global_load_lds(
      (__attribute__((address_space(1))) void*)(g),
      (__attribute__((address_space(3))) void*)(l), 16, 0, 0);
}

__device__ __forceinline__ void block_barrier() {
  asm volatile("" ::: "memory");
  __builtin_amdgcn_sched_barrier(0);
  __builtin_amdgcn_s_barrier();
  __builtin_amdgcn_sched_barrier(0);
  asm volatile("" ::: "memory");
}

// ---------------------------------------------------------------------------
// Batched transpose: in fp32 [batch][R][Cc] -> out bf16 [batch*Cc + c][R]
// ---------------------------------------------------------------------------
__global__ __launch_bounds__(256) void transpose_w(
    const float* __restrict__ in, unsigned short* __restrict__ out,
    int R, int Cc) {
  __shared__ float tile[32][33];
  const int batch = blockIdx.z;
  const float* ip = in + (size_t)batch * R * Cc;
  unsigned short* op = out + (size_t)batch * R * Cc;
  const int c0 = blockIdx.x * 32, r0 = blockIdx.y * 32;
  const int tx = threadIdx.x, ty = threadIdx.y;  // 32 x 8
#pragma unroll
  for (int i = 0; i < 32; i += 8)
    tile[ty + i][tx] = ip[(size_t)(r0 + ty + i) * Cc + c0 + tx];
  __syncthreads();
#pragma unroll
  for (int i = 0; i < 32; i += 8)
    op[(size_t)(c0 + ty + i) * R + r0 + tx] = f2bf(tile[tx][ty + i]);
}

// Merged Wq/Wk/Wv transpose: z in [0,48), source picked by z/16.
__global__ __launch_bounds__(256) void transpose_qkv(
    const float* __restrict__ Wq, const float* __restrict__ Wk,
    const float* __restrict__ Wv, unsigned short* __restrict__ out) {
  __shared__ float tile[32][33];
  const int z = blockIdx.z;
  const float* src = (z < 16) ? Wq : (z < 32 ? Wk : Wv);
  const int batch = z & 15;
  const int R = 1024, Cc = 64;
  const float* ip = src + (size_t)batch * R * Cc;
  unsigned short* op = out + (size_t)z * R * Cc;
  const int c0 = blockIdx.x * 32, r0 = blockIdx.y * 32;
  const int tx = threadIdx.x, ty = threadIdx.y;
#pragma unroll
  for (int i = 0; i < 32; i += 8)
    tile[ty + i][tx] = ip[(size_t)(r0 + ty + i) * Cc + c0 + tx];
  __syncthreads();
#pragma unroll
  for (int i = 0; i < 32; i += 8)
    op[(size_t)(c0 + ty + i) * R + r0 + tx] = f2bf(tile[tx][ty + i]);
}

// ---------------------------------------------------------------------------
// LayerNorm over rows of 1024, fp32 in -> bf16 out.
// ---------------------------------------------------------------------------
__global__ __launch_bounds__(256) void ln_kernel(
    const float* __restrict__ x, const float* __restrict__ g,
    const float* __restrict__ bta, unsigned short* __restrict__ out) {
  const int C = 1024;
  const int row = blockIdx.x, tid = threadIdx.x;
  const float4 v = ((const float4*)(x + (size_t)row * C))[tid];
  float s  = v.x + v.y + v.z + v.w;
  float ss = v.x * v.x + v.y * v.y + v.z * v.z + v.w * v.w;
#pragma unroll
  for (int off = 32; off > 0; off >>= 1) {
    s  += __shfl_down(s, off);
    ss += __shfl_down(ss, off);
  }
  __shared__ float r0[4], r1[4];
  const int wave = tid >> 6, lane = tid & 63;
  if (lane == 0) { r0[wave] = s; r1[wave] = ss; }
  __syncthreads();
  s  = r0[0] + r0[1] + r0[2] + r0[3];
  ss = r1[0] + r1[1] + r1[2] + r1[3];
  const float mu   = s * (1.0f / C);
  const float var  = ss * (1.0f / C) - mu * mu;
  const float rstd = rsqrtf(var + 1e-5f);
  const float4 gv = ((const float4*)g)[tid];
  const float4 bv = ((const float4*)bta)[tid];
  ushort4 o;
  o.x = f2bf((v.x - mu) * rstd * gv.x + bv.x);
  o.y = f2bf((v.y - mu) * rstd * gv.y + bv.y);
  o.z = f2bf((v.z - mu) * rstd * gv.z + bv.z);
  o.w = f2bf((v.w - mu) * rstd * gv.w + bv.w);
  ((ushort4*)(out + (size_t)row * C))[tid] = o;
}

// ---------------------------------------------------------------------------
// 128x64-tile latency GEMM (round-6 verified): 512 blocks = 2 blocks/CU.
// ---------------------------------------------------------------------------
__global__ __launch_bounds__(256, 2) void gemm_lat2(
    const unsigned short* __restrict__ A, const unsigned short* __restrict__ BT,
    float* __restrict__ Cout, const float* __restrict__ bias,
    const float* __restrict__ resid, int M, int N, int K) {
  __shared__ __align__(16) unsigned short As[3][8192];
  __shared__ __align__(16) unsigned short Bs[3][4096];
  const int tid = threadIdx.x;
  const int lane = tid & 63, wave = tid >> 6;
  const int wm = wave >> 1, wn = wave & 1;
  const int lr = lane & 15, lg = lane >> 4;

  const int nwg = gridDim.x;
  const int cpx = nwg >> 3;
  const int swz = ((int)blockIdx.x & 7) * cpx + ((int)blockIdx.x >> 3);
  const int Nt = N >> 6;
  const int g4 = swz / (4 * Nt);
  const int rem = swz - g4 * 4 * Nt;
  const int m0 = (g4 * 4 + (rem & 3)) << 7;
  const int n0 = (rem >> 2) << 6;

  const int srow = tid >> 3;
  const int sc = ((tid & 7) ^ (srow & 7)) << 3;
  const unsigned short* Ag = A + (size_t)(m0 + srow) * K + sc;
  const unsigned short* Bg = BT + (size_t)(n0 + srow) * K + sc;
  const size_t rskip = (size_t)32 * K;

  f32x4 acc[4][2] = {};
  const int nkt = K >> 6;

#define STG(T, B)                                                          \
  {                                                                        \
    const int kt_ = (T) << 6;                                              \
    _Pragma("unroll")                                                      \
    for (int j = 0; j < 4; ++j)                                            \
      async16(Ag + kt_ + (size_t)j * rskip, &As[B][j * 2048 + tid * 8]);   \
    async16(Bg + kt_, &Bs[B][tid * 8]);                                    \
    async16(Bg + kt_ + rskip, &Bs[B][2048 + tid * 8]);                     \
  }

  STG(0, 0);
  STG(1, 1);

  for (int t = 0; t < nkt; ++t) {
    const int buf = t % 3;
    if (t + 1 < nkt) asm volatile("s_waitcnt vmcnt(6)" ::: "memory");
    else             asm volatile("s_waitcnt vmcnt(0)" ::: "memory");
    block_barrier();
    if (t + 2 < nkt) {
      int sb = buf + 2; if (sb >= 3) sb -= 3;
      STG(t + 2, sb);
    }
#pragma unroll
    for (int kh = 0; kh < 2; ++kh) {
      const int kc = ((kh * 4 + lg) ^ (lr & 7)) << 3;
      bf16x8 afr[4], bfr[2];
#pragma unroll
      for (int fm = 0; fm < 4; fm++)
        afr[fm] = *(const bf16x8*)&As[buf][(wm * 64 + fm * 16 + lr) * 64 + kc];
#pragma unroll
      for (int fn = 0; fn < 2; fn++)
        bfr[fn] = *(const bf16x8*)&Bs[buf][(wn * 32 + fn * 16 + lr) * 64 + kc];
#pragma unroll
      for (int fm = 0; fm < 4; fm++)
#pragma unroll
        for (int fn = 0; fn < 2; fn++)
          acc[fm][fn] = __builtin_amdgcn_mfma_f32_16x16x32_bf16(
              afr[fm], bfr[fn], acc[fm][fn], 0, 0, 0);
    }
  }
#undef STG

#pragma unroll
  for (int fn = 0; fn < 2; fn++) {
    const int col = n0 + wn * 32 + fn * 16 + lr;
    const float bv = bias[col];
#pragma unroll
    for (int fm = 0; fm < 4; fm++) {
      const int row0 = m0 + wm * 64 + fm * 16 + lg * 4;
#pragma unroll
      for (int r = 0; r < 4; r++) {
        const size_t idx = (size_t)(row0 + r) * N + col;
        Cout[idx] = acc[fm][fn][r] + bv + resid[idx];
      }
    }
  }
}

// ---------------------------------------------------------------------------
// Split-K reduce (4 planes bf16): out[i] = sum_p P[p][i] + bias + out[i].
// ---------------------------------------------------------------------------
__global__ __launch_bounds__(256) void reduce_add4(
    const unsigned short* __restrict__ p01, const unsigned short* __restrict__ p23,
    const float* __restrict__ bias, float* __restrict__ out, int n4) {
  const int stride = gridDim.x * 256;
#define BF(u) __uint_as_float(((unsigned)(u)) << 16)
  for (int i = blockIdx.x * 256 + threadIdx.x; i < n4; i += stride) {
    const ushort4 a = ((const ushort4*)p01)[i];
    const ushort4 b = ((const ushort4*)p01)[i + n4];
    const ushort4 c = ((const ushort4*)p23)[i];
    const ushort4 d = ((const ushort4*)p23)[i + n4];
    const float4 r = ((const float4*)out)[i];
    const float4 bv = ((const float4*)bias)[i & 255];
    float4 o;
    o.x = (BF(a.x) + BF(b.x)) + (BF(c.x) + BF(d.x)) + r.x + bv.x;
    o.y = (BF(a.y) + BF(b.y)) + (BF(c.y) + BF(d.y)) + r.y + bv.y;
    o.z = (BF(a.z) + BF(b.z)) + (BF(c.z) + BF(d.z)) + r.z + bv.z;
    o.w = (BF(a.w) + BF(b.w)) + (BF(c.w) + BF(d.w)) + r.w + bv.w;
    ((float4*)out)[i] = o;
  }
#undef BF
}

// ---------------------------------------------------------------------------
// 256x256 8-phase deep-pipelined GEMM, optional split-K, with COALESCED
// LDS-roundtrip epilogue.
// EPI: 2 = relu(+bias) -> bf16 ; 4 = QKV split (Q cols pre-scaled by
//      0.125*log2e) ; 5 = bf16 partial planes.
// ---------------------------------------------------------------------------
template <int EPI, int SPLITK>
__global__ __launch_bounds__(512, 2) void gemm8p(
    const unsigned short* __restrict__ A, const unsigned short* __restrict__ BT,
    void* __restrict__ Cout, void* __restrict__ Cout2,
    const float* __restrict__ bias, int M, int N, int K) {
  __shared__ __align__(16) unsigned short As[2][2][8192];
  __shared__ __align__(16) unsigned short Bs[2][2][8192];
  const int tid = threadIdx.x;
  const int lane = tid & 63;
  const int wave = tid >> 6;
  const int wm = wave >> 2, wn = wave & 3;  // 2 x 4 wave grid
  const int lr = lane & 15, lg = lane >> 4;

  const int nwg = gridDim.x;
  const int cpx = nwg >> 3;
  const int swz = ((int)blockIdx.x & 7) * cpx + ((int)blockIdx.x >> 3);
  int tile = swz, ks = 0;
  if (SPLITK > 1) {
    const int tilesPer = nwg / SPLITK;
    ks = swz / tilesPer;
    tile = swz - ks * tilesPer;
  }
  const int Ksl = K / SPLITK;
  const int k0 = ks * Ksl;
  const int Nt = N >> 8;
  const int g4 = tile / (4 * Nt);
  const int rem = tile - g4 * 4 * Nt;
  const int m0 = (g4 * 4 + (rem & 3)) << 8;
  const int n0 = (rem >> 2) << 8;

  const int srow = tid >> 2;
  const int scg = ((tid & 3) ^ ((srow >> 1) & 3)) << 3;
  const unsigned short* Ag = A + (size_t)(m0 + srow) * K + k0 + scg;
  const unsigned short* Bg = BT + (size_t)(n0 + srow) * K + k0 + scg;
  const size_t rskip = (size_t)128 * K;
  const int l8 = tid * 8;

  const int kch = (lg ^ ((lr >> 1) & 3)) << 3;

  f32x4 acc[8][4] = {};
  bf16x8 afr[4], bfr[4];
  const int nkt = Ksl >> 6;

  async16(Ag, &As[0][0][l8]);            async16(Ag + rskip, &As[0][0][l8 + 4096]);
  async16(Bg, &Bs[0][0][l8]);            async16(Bg + rskip, &Bs[0][0][l8 + 4096]);
  async16(Ag + 32, &As[0][1][l8]);       async16(Ag + 32 + rskip, &As[0][1][l8 + 4096]);
  async16(Bg + 32, &Bs[0][1][l8]);       async16(Bg + 32 + rskip, &Bs[0][1][l8 + 4096]);
  async16(Ag + 64, &As[1][0][l8]);       async16(Ag + 64 + rskip, &As[1][0][l8 + 4096]);
  async16(Bg + 64, &Bs[1][0][l8]);       async16(Bg + 64 + rskip, &Bs[1][0][l8 + 4096]);
  asm volatile("s_waitcnt vmcnt(4)" ::: "memory");
  block_barrier();

  for (int t = 0; t < nkt; ++t) {
    const int buf = t & 1, nbuf = buf ^ 1;
    const int kt1 = (t + 1) << 6, kt2 = (t + 2) << 6;
    const bool s1 = (t + 1 < nkt), s2 = (t + 2 < nkt);

    // ---- phase 1: ks=0, mh=0 ----
#pragma unroll
    for (int fm = 0; fm < 4; fm++)
      afr[fm] = *(const bf16x8*)&As[buf][0][(wm * 128 + fm * 16 + lr) * 32 + kch];
#pragma unroll
    for (int fn = 0; fn < 4; fn++)
      bfr[fn] = *(const bf16x8*)&Bs[buf][0][(wn * 64 + fn * 16 + lr) * 32 + kch];
    if (s1) {
      async16(Ag + kt1 + 32, &As[nbuf][1][l8]);
      async16(Ag + kt1 + 32 + rskip, &As[nbuf][1][l8 + 4096]);
    }
    block_barrier();
    __builtin_amdgcn_s_setprio(1);
#pragma unroll
    for (int fm = 0; fm < 4; fm++)
#pragma unroll
      for (int fn = 0; fn < 4; fn++)
        acc[fm][fn] = __builtin_amdgcn_mfma_f32_16x16x32_bf16(afr[fm], bfr[fn], acc[fm][fn], 0, 0, 0);
    __builtin_amdgcn_s_setprio(0);
    block_barrier();

    // ---- phase 2: ks=0, mh=1 ----
#pragma unroll
    for (int fm = 0; fm < 4; fm++)
      afr[fm] = *(const bf16x8*)&As[buf][0][(wm * 128 + 64 + fm * 16 + lr) * 32 + kch];
    if (s1) {
      async16(Bg + kt1 + 32, &Bs[nbuf][1][l8]);
      async16(Bg + kt1 + 32 + rskip, &Bs[nbuf][1][l8 + 4096]);
    }
    block_barrier();
    __builtin_amdgcn_s_setprio(1);
#pragma unroll
    for (int fm = 0; fm < 4; fm++)
#pragma unroll
      for (int fn = 0; fn < 4; fn++)
        acc[4 + fm][fn] = __builtin_amdgcn_mfma_f32_16x16x32_bf16(afr[fm], bfr[fn], acc[4 + fm][fn], 0, 0, 0);
    __builtin_amdgcn_s_setprio(0);
    block_barrier();

    // ---- phase 3: ks=1, mh=0 ----
#pragma unroll
    for (int fm = 0; fm < 4; fm++)
      afr[fm] = *(const bf16x8*)&As[buf][1][(wm * 128 + fm * 16 + lr) * 32 + kch];
#pragma unroll
    for (int fn = 0; fn < 4; fn++)
      bfr[fn] = *(const bf16x8*)&Bs[buf][1][(wn * 64 + fn * 16 + lr) * 32 + kch];
    if (s2) {
      async16(Ag + kt2, &As[buf][0][l8]);
      async16(Ag + kt2 + rskip, &As[buf][0][l8 + 4096]);
    }
    block_barrier();
    __builtin_amdgcn_s_setprio(1);
#pragma unroll
    for (int fm = 0; fm < 4; fm++)
#pragma unroll
      for (int fn = 0; fn < 4; fn++)
        acc[fm][fn] = __builtin_amdgcn_mfma_f32_16x16x32_bf16(afr[fm], bfr[fn], acc[fm][fn], 0, 0, 0);
    __builtin_amdgcn_s_setprio(0);
    block_barrier();

    // ---- phase 4: ks=1, mh=1 ----
#pragma unroll
    for (int fm = 0; fm < 4; fm++)
      afr[fm] = *(const bf16x8*)&As[buf][1][(wm * 128 + 64 + fm * 16 + lr) * 32 + kch];
    if (s2) {
      async16(Bg + kt2, &Bs[buf][0][l8]);
      async16(Bg + kt2 + rskip, &Bs[buf][0][l8 + 4096]);
    }
    block_barrier();
    __builtin_amdgcn_s_setprio(1);
#pragma unroll
    for (int fm = 0; fm < 4; fm++)
#pragma unroll
      for (int fn = 0; fn < 4; fn++)
        acc[4 + fm][fn] = __builtin_amdgcn_mfma_f32_16x16x32_bf16(afr[fm], bfr[fn], acc[4 + fm][fn], 0, 0, 0);
    __builtin_amdgcn_s_setprio(0);
    if (s2) asm volatile("s_waitcnt vmcnt(4)" ::: "memory");
    else    asm volatile("s_waitcnt vmcnt(0)" ::: "memory");
    block_barrier();
  }

  // ---- coalesced epilogue: acc -> LDS (bf16, XOR-swizzled) -> wide stores.
  unsigned short* wlds = &As[0][0][0] + wave * 4096;
  const bool vpath = (EPI == 4) && (n0 >= 2048);

#pragma unroll
  for (int mh = 0; mh < 2; ++mh) {
#pragma unroll
    for (int fn = 0; fn < 4; fn++) {
      const int col = n0 + wn * 64 + fn * 16 + lr;
      float bv = 0.0f;
      if (EPI == 2) bv = bias[col];
      const bool qscale = (EPI == 4) && (col < 1024);
#pragma unroll
      for (int fm = 0; fm < 4; fm++) {
#pragma unroll
        for (int r = 0; r < 4; r++) {
          float v = acc[mh * 4 + fm][fn][r];
          if (EPI == 2) v = fmaxf(v + bv, 0.0f);
          if (qscale) v *= 0.18033688011112042f;  // 0.125 * log2(e)
          wlds[(fm * 16 + lg * 4 + r) * 64 + (((fn ^ lg) << 4) | lr)] = f2bf(v);
        }
      }
    }
    asm volatile("s_waitcnt lgkmcnt(0)" ::: "memory");
    __builtin_amdgcn_sched_barrier(0);

    if (vpath) {
      const int colw = lane;
      const int fnr = colw >> 4, cin = colw & 15;
      unsigned short* dst = (unsigned short*)Cout2 +
          (size_t)(n0 - 2048 + wn * 64 + colw) * 4096 +
          (m0 + wm * 128 + mh * 64);
#pragma unroll
      for (int p = 0; p < 8; ++p) {
        unsigned short tmp[8];
#pragma unroll
        for (int j = 0; j < 8; ++j) {
          const int lrow = p * 8 + j;
          tmp[j] = wlds[lrow * 64 + (((fnr ^ ((lrow >> 2) & 3)) << 4) | cin)];
        }
        *(ushort4*)(dst + p * 8)     = *(ushort4*)&tmp[0];
        *(ushort4*)(dst + p * 8 + 4) = *(ushort4*)&tmp[4];
      }
    } else {
      const int fnr = (lane & 7) >> 1;
      const int coff = (lane & 1) << 3;
      const int gcol = n0 + wn * 64 + (lane & 7) * 8;
      const int Nst = (EPI == 4) ? 2048 : N;
      unsigned short* base;
      if (EPI == 5)
        base = (unsigned short*)(ks < 2 ? Cout : Cout2) + (size_t)(ks & 1) * M * N;
      else
        base = (unsigned short*)Cout;
#pragma unroll
      for (int p = 0; p < 8; ++p) {
        const int lrow = p * 8 + (lane >> 3);
        const bf16x8 v = *(const bf16x8*)
            &wlds[lrow * 64 + (((fnr ^ ((lrow >> 2) & 3)) << 4) | coff)];
        const size_t grow = (size_t)(m0 + wm * 128 + mh * 64 + lrow);
        *(bf16x8*)(base + grow * Nst + gcol) = v;
      }
    }
    asm volatile("s_waitcnt lgkmcnt(0)" ::: "memory");
    __builtin_amdgcn_sched_barrier(0);
  }
}

// ---------------------------------------------------------------------------
// Flash attention (causal), swapped-operand, exp2 softmax, MFMA-lsum.
// NEW: 512-thread blocks — waves 0-3 own q-tile 2k, waves 4-7 own q-tile
// 2k+1 (contiguous 128 q-rows), SHARING the staged K/V s-blocks:
//   - staging halves (1 async16/thread per 8KB tile; vmcnt(2))
//   - barrier-iterations per CU halve
//   - LDS 48 KB -> 3 blocks/CU = 24 waves/CU
// Sub-unit 0 idles exactly 1 iteration (its diagonal is one s-block short).
// Grid 512: id&7 = bh&7 (XCD L2 grouping), pair index kidx descending (LPT).
// ---------------------------------------------------------------------------
__global__ __launch_bounds__(512, 6) void attn_kernel(
    const unsigned short* __restrict__ qk, const unsigned short* __restrict__ vT,
    unsigned short* __restrict__ o) {
  const int T = 2048, C = 1024, QKS = 2048;
  const int tid = threadIdx.x;
  const int wave = tid >> 6, lane = tid & 63;
  const int qsub = wave >> 2;            // which q-tile of the pair
  const int wv = wave & 3;               // wave within sub-unit
  const int lr = lane & 15, lg = lane >> 4;

  // decode XCD-grouped LPT mapping (512 blocks)
  const int id = (int)blockIdx.x;
  const int rest = id >> 3;              // [0,64)
  const int bhHi = rest & 3;
  const int kidx = 15 - (rest >> 2);     // pair index, longest first
  const int bh = (bhHi << 3) | (id & 7);
  const int b = bh >> 4, hh = bh & 15;

  const size_t rowb = (size_t)b * T * QKS;
  const int qcol = hh * 64;
  const int kcol = 1024 + hh * 64;
  const int vrow0 = hh * 64;
  const size_t bT = (size_t)b * T;
  const int swe = (lr & 7) << 3;

  __shared__ __align__(16) unsigned short Ks[2][64 * 64];
  __shared__ __align__(16) unsigned short Vs[2][64 * 64];
  __shared__ __align__(16) unsigned short Ps[8][16][64];

  // staging: 512 threads cover one 64x64 tile (1 x 16B chunk each)
  const int rw = tid >> 3;
  const int c8 = ((tid & 7) ^ (rw & 7)) << 3;

  const int myqt = kidx * 2 + qsub;      // diagonal s-block of this sub-unit
  const int qtB = kidx * 2 + 1;          // loop bound (longer sub-unit)
  const int qbase = myqt * 64 + wv * 16;
  const int trow = qbase + lr;
  const int pswz = lr & 7;               // Ps chunk XOR key

  U8 ones;
#pragma unroll
  for (int j = 0; j < 8; j++) ones.u[j] = 0x3F80;  // bf16 1.0

  U8 qf[2];
#pragma unroll
  for (int j = 0; j < 2; j++)
    qf[j].v = *(const bf16x8*)(qk + rowb + (size_t)trow * QKS + qcol + j * 32 + lg * 8);
  asm volatile("s_waitcnt vmcnt(0)" ::: "memory");

  async16(qk + rowb + (size_t)rw * QKS + kcol + c8, Ks[0] + tid * 8);
  async16(vT + (size_t)(vrow0 + rw) * 4096 + bT + c8, Vs[0] + tid * 8);

  f32x4 oa[4] = {};
  f32x4 oas = {};               // lsum accumulator via ones-row MFMA
  float mrun = -1e30f;
  int cur = 0;

  for (int sb = 0; sb <= qtB; ++sb) {
    if (sb < qtB) {
      const int s1 = (sb + 1) * 64;
      const int nb = cur ^ 1;
      async16(qk + rowb + (size_t)(s1 + rw) * QKS + kcol + c8, Ks[nb] + tid * 8);
      async16(vT + (size_t)(vrow0 + rw) * 4096 + bT + s1 + c8, Vs[nb] + tid * 8);
      asm volatile("s_waitcnt vmcnt(2)" ::: "memory");
    } else {
      asm volatile("s_waitcnt vmcnt(0)" ::: "memory");
    }
    block_barrier();

    if (sb <= myqt) {
      const unsigned short* Kc = Ks[cur];
      const unsigned short* Vc = Vs[cur];
      const int s0 = sb * 64;

      f32x4 sa[4] = {};
      __builtin_amdgcn_s_setprio(1);
#pragma unroll
      for (int j = 0; j < 2; j++) {
#pragma unroll
        for (int mf = 0; mf < 4; mf++) {
          U8 kf;
          kf.v = *(const bf16x8*)(Kc + (mf * 16 + lr) * 64 + ((j * 32 + lg * 8) ^ swe));
          sa[mf] = __builtin_amdgcn_mfma_f32_16x16x32_bf16(kf.v, qf[j].v, sa[mf], 0, 0, 0);
        }
      }
      __builtin_amdgcn_s_setprio(0);
      float sv[16];
#pragma unroll
      for (int mf = 0; mf < 4; mf++)
#pragma unroll
        for (int r = 0; r < 4; r++) sv[mf * 4 + r] = sa[mf][r];  // log2-scaled

      if (sb == myqt) {
#pragma unroll
        for (int mf = 0; mf < 4; mf++)
#pragma unroll
          for (int r = 0; r < 4; r++)
            if (s0 + mf * 16 + lg * 4 + r > trow) sv[mf * 4 + r] = -1e30f;
      }

      // max over 16 (max3-shaped) + 2 cross-lane steps
      const float g0 = fmaxf(fmaxf(sv[0], sv[1]), sv[2]);
      const float g1 = fmaxf(fmaxf(sv[3], sv[4]), sv[5]);
      const float g2 = fmaxf(fmaxf(sv[6], sv[7]), sv[8]);
      const float g3 = fmaxf(fmaxf(sv[9], sv[10]), sv[11]);
      const float g4 = fmaxf(fmaxf(sv[12], sv[13]), sv[14]);
      float tm = fmaxf(fmaxf(fmaxf(fmaxf(g0, g1), g2), fmaxf(g3, g4)), sv[15]);
      tm = fmaxf(tm, __shfl_xor(tm, 16));
      tm = fmaxf(tm, __shfl_xor(tm, 32));

      if (!__all(tm <= mrun + 8.0f)) {  // defer-max (log2 units)
        const float mn = fmaxf(mrun, tm);
        const float corr = __builtin_amdgcn_exp2f(mrun - mn);
#pragma unroll
        for (int c = 0; c < 4; c++)
#pragma unroll
          for (int r = 0; r < 4; r++) oa[c][r] *= corr;
#pragma unroll
        for (int r = 0; r < 4; r++) oas[r] *= corr;
        mrun = mn;
      }

#pragma unroll
      for (int i = 0; i < 16; i++)
        sv[i] = __builtin_amdgcn_exp2f(sv[i] - mrun);

      // P -> LDS, chunk-XOR swizzled (involution by lr&7)
#pragma unroll
      for (int mf = 0; mf < 4; mf++) {
        ushort4 w;
        w.x = f2bf(sv[mf * 4 + 0]);
        w.y = f2bf(sv[mf * 4 + 1]);
        w.z = f2bf(sv[mf * 4 + 2]);
        w.w = f2bf(sv[mf * 4 + 3]);
        const int wchunk = (mf * 2 + (lg >> 1)) ^ pswz;
        *(ushort4*)&Ps[wave][lr][wchunk * 8 + (lg & 1) * 4] = w;
      }
      asm volatile("" ::: "memory");
      U8 pb[2];
      pb[0].v = *(const bf16x8*)&Ps[wave][lr][(lg ^ pswz) * 8];
      pb[1].v = *(const bf16x8*)&Ps[wave][lr][((4 + lg) ^ pswz) * 8];
      asm volatile("" ::: "memory");

      __builtin_amdgcn_s_setprio(1);
#pragma unroll
      for (int c = 0; c < 4; c++) {
#pragma unroll
        for (int ks = 0; ks < 2; ks++) {
          U8 vf;
          vf.v = *(const bf16x8*)(Vc + (c * 16 + lr) * 64 + ((ks * 32 + lg * 8) ^ swe));
          oa[c] = __builtin_amdgcn_mfma_f32_16x16x32_bf16(vf.v, pb[ks].v, oa[c], 0, 0, 0);
        }
      }
      // lsum contribution: ones-row MFMA (column sums of P)
      oas = __builtin_amdgcn_mfma_f32_16x16x32_bf16(ones.v, pb[0].v, oas, 0, 0, 0);
      oas = __builtin_amdgcn_mfma_f32_16x16x32_bf16(ones.v, pb[1].v, oas, 0, 0, 0);
      __builtin_amdgcn_s_setprio(0);
    }

    block_barrier();
    cur ^= 1;
  }

  const float inv = 1.0f / oas[0];
#pragma unroll
  for (int c = 0; c < 4; c++) {
    ushort4 ov;
    ov.x = f2bf(oa[c][0] * inv);
    ov.y = f2bf(oa[c][1] * inv);
    ov.z = f2bf(oa[c][2] * inv);
    ov.w = f2bf(oa[c][3] * inv);
    *(ushort4*)(o + (size_t)(bT + trow) * C + hh * 64 + c * 16 + lg * 4) = ov;
  }
}

// ---------------------------------------------------------------------------
// Orchestration.  Workspace lifetimes (80 MB):
//   0-6 WqkvT (dead after QKV) | 6-8 WpT (dead after proj) | 8-16 W1T (dead
//   after FFN1) | 16-24 W2T (thru FFN2) | 24-32 h (dead after QKV) |
//   32-48 qkb, 48-56 vTb (dead after attn) | 56-64 att -> h2 |
//   24-56 ff1 after FFN1 | x1 = d_out | FFN2 bf16 partials: 0-16 & 64-80.
// ---------------------------------------------------------------------------
extern "C" void kernel_launch(void* const* d_in, const int* in_sizes, int n_in,
                              void* d_out, int out_size, void* d_ws, size_t ws_size,
                              hipStream_t stream) {
  (void)in_sizes; (void)n_in; (void)out_size; (void)ws_size;
  const int T = 2048, C = 1024, M = 2 * T, C4 = 4 * C;

  const float* x     = (const float*)d_in[0];
  const float* Wq    = (const float*)d_in[1];
  const float* Wk    = (const float*)d_in[2];
  const float* Wv    = (const float*)d_in[3];
  const float* Wproj = (const float*)d_in[4];
  const float* bproj = (const float*)d_in[5];
  const float* W1    = (const float*)d_in[6];
  const float* b1    = (const float*)d_in[7];
  const float* W2    = (const float*)d_in[8];
  const float* b2    = (const float*)d_in[9];
  const float* ln1g  = (const float*)d_in[10];
  const float* ln1b  = (const float*)d_in[11];
  const float* ln2g  = (const float*)d_in[12];
  const float* ln2b  = (const float*)d_in[13];
  float* out = (float*)d_out;

  char* ws = (char*)d_ws;
  const size_t MBy = (size_t)1 << 20;
  unsigned short* WqkvT = (unsigned short*)(ws + 0 * MBy);
  unsigned short* WpT = (unsigned short*)(ws + 6 * MBy);
  unsigned short* W1T = (unsigned short*)(ws + 8 * MBy);
  unsigned short* W2T = (unsigned short*)(ws + 16 * MBy);
  unsigned short* h   = (unsigned short*)(ws + 24 * MBy);
  unsigned short* qkb = (unsigned short*)(ws + 32 * MBy);
  unsigned short* vTb = (unsigned short*)(ws + 48 * MBy);
  unsigned short* att = (unsigned short*)(ws + 56 * MBy);
  float* x1 = out;                                    // x1 lives in d_out
  unsigned short* h2  = att;
  unsigned short* ff1 = h;
  unsigned short* ffP01 = (unsigned short*)(ws + 0 * MBy);   // planes 0,1
  unsigned short* ffP23 = (unsigned short*)(ws + 64 * MBy);  // planes 2,3

  const dim3 tb(32, 8);
  transpose_qkv<<<dim3(2, 32, 48), tb, 0, stream>>>(Wq, Wk, Wv, WqkvT);
  transpose_w<<<dim3(32, 32, 1), tb, 0, stream>>>(Wproj, WpT, 1024, 1024);
  transpose_w<<<dim3(128, 32, 1), tb, 0, stream>>>(W1, W1T, 1024, 4096);
  transpose_w<<<dim3(32, 128, 1), tb, 0, stream>>>(W2, W2T, 4096, 1024);

  ln_kernel<<<M, 256, 0, stream>>>(x, ln1g, ln1b, h);

  // Fused QKV (8-phase 256^2): Q cols pre-scaled by 0.125*log2e
  gemm8p<4, 1><<<192, 512, 0, stream>>>(h, WqkvT, qkb, vTb, nullptr, M, 3072, C);

  // attn: 512 blocks x 512 thr (2 q-tiles/block), XCD-grouped + LPT
  attn_kernel<<<512, 512, 0, stream>>>(qkb, vTb, att);

  // proj (+bproj +x) -> x1 (d_out)
  gemm_lat2<<<512, 256, 0, stream>>>(att, WpT, x1, bproj, x, M, C, C);

  ln_kernel<<<M, 256, 0, stream>>>(x1, ln2g, ln2b, h2);

  // FFN1 (8-phase 256^2): relu(h2 @ W1 + b1) -> bf16
  gemm8p<2, 1><<<256, 512, 0, stream>>>(h2, W1T, ff1, nullptr, b1, M, C4, C);

  // FFN2: split-K=4 8-phase partials (bf16) + fused reduce (+b2 +x1 in-place)
  gemm8p<5, 4><<<256, 512, 0, stream>>>(ff1, W2T, ffP01, ffP23, nullptr, M, C, C4);
  reduce_add4<<<2048, 256, 0, stream>>>(ffP01, ffP23, b2, out, M * C / 4);
}

// Round 17
// 213.038 us; speedup vs baseline: 1.0441x; 1.0441x over previous
//
#include <hip/hip_runtime.h>

// ---------------------------------------------------------------------------
// Types / helpers
// ---------------------------------------------------------------------------
typedef __bf16 bf16x8 __attribute__((ext_vector_type(8)));
typedef float  f32x4  __attribute__((ext_vector_type(4)));

union U8 { bf16x8 v; __bf16 e[8]; unsigned short u[8]; };

// Native HW conversion (v_cvt_*_bf16), RNE.
__device__ __forceinline__ unsigned short f2bf(float f) {
  union { __bf16 b; unsigned short u; } c;
  c.b = (__bf16)f;
  return c.u;
}

__device__ __forceinline__ void async16(const void* g, void* l) {
  __builtin_amdgcn_global_load_lds(
      (__attribute__((address_space(1))) void*)(g),
      (__attribute__((address_space(3))) void*)(l), 16, 0, 0);
}

__device__ __forceinline__ void block_barrier() {
  asm volatile("" ::: "memory");
  __builtin_amdgcn_sched_barrier(0);
  __builtin_amdgcn_s_barrier();
  __builtin_amdgcn_sched_barrier(0);
  asm volatile("" ::: "memory");
}

// ---------------------------------------------------------------------------
// Merged Wq/Wk/Wv transpose: z in [0,48), source picked by z/16.
// ---------------------------------------------------------------------------
__global__ __launch_bounds__(256) void transpose_qkv(
    const float* __restrict__ Wq, const float* __restrict__ Wk,
    const float* __restrict__ Wv, unsigned short* __restrict__ out) {
  __shared__ float tile[32][33];
  const int z = blockIdx.z;
  const float* src = (z < 16) ? Wq : (z < 32 ? Wk : Wv);
  const int batch = z & 15;
  const int R = 1024, Cc = 64;
  const float* ip = src + (size_t)batch * R * Cc;
  unsigned short* op = out + (size_t)z * R * Cc;
  const int c0 = blockIdx.x * 32, r0 = blockIdx.y * 32;
  const int tx = threadIdx.x, ty = threadIdx.y;
#pragma unroll
  for (int i = 0; i < 32; i += 8)
    tile[ty + i][tx] = ip[(size_t)(r0 + ty + i) * Cc + c0 + tx];
  __syncthreads();
#pragma unroll
  for (int i = 0; i < 32; i += 8)
    op[(size_t)(c0 + ty + i) * R + r0 + tx] = f2bf(tile[tx][ty + i]);
}

// ---------------------------------------------------------------------------
// Merged Wproj/W1/W2 transpose: one dispatch, flat block-id decode.
//   id < 1024           : Wproj (1024x1024) -> WpT
//   id < 1024+4096      : W1    (1024x4096) -> W1T
//   else                : W2    (4096x1024) -> W2T
// ---------------------------------------------------------------------------
__global__ __launch_bounds__(256) void transpose_rest(
    const float* __restrict__ Wproj, const float* __restrict__ W1,
    const float* __restrict__ W2, unsigned short* __restrict__ WpT,
    unsigned short* __restrict__ W1T, unsigned short* __restrict__ W2T) {
  __shared__ float tile[32][33];
  const int id = (int)blockIdx.x;
  const float* ip;
  unsigned short* op;
  int R, Cc, bx, by;
  if (id < 1024) {
    ip = Wproj; op = WpT; R = 1024; Cc = 1024;
    bx = id & 31; by = id >> 5;
  } else if (id < 1024 + 4096) {
    const int t = id - 1024;
    ip = W1; op = W1T; R = 1024; Cc = 4096;
    bx = t & 127; by = t >> 7;
  } else {
    const int t = id - 5120;
    ip = W2; op = W2T; R = 4096; Cc = 1024;
    bx = t & 31; by = t >> 5;
  }
  const int c0 = bx * 32, r0 = by * 32;
  const int tx = threadIdx.x, ty = threadIdx.y;  // 32 x 8
#pragma unroll
  for (int i = 0; i < 32; i += 8)
    tile[ty + i][tx] = ip[(size_t)(r0 + ty + i) * Cc + c0 + tx];
  __syncthreads();
#pragma unroll
  for (int i = 0; i < 32; i += 8)
    op[(size_t)(c0 + ty + i) * R + r0 + tx] = f2bf(tile[tx][ty + i]);
}

// ---------------------------------------------------------------------------
// LayerNorm over rows of 1024, fp32 in -> bf16 out.
// ---------------------------------------------------------------------------
__global__ __launch_bounds__(256) void ln_kernel(
    const float* __restrict__ x, const float* __restrict__ g,
    const float* __restrict__ bta, unsigned short* __restrict__ out) {
  const int C = 1024;
  const int row = blockIdx.x, tid = threadIdx.x;
  const float4 v = ((const float4*)(x + (size_t)row * C))[tid];
  float s  = v.x + v.y + v.z + v.w;
  float ss = v.x * v.x + v.y * v.y + v.z * v.z + v.w * v.w;
#pragma unroll
  for (int off = 32; off > 0; off >>= 1) {
    s  += __shfl_down(s, off);
    ss += __shfl_down(ss, off);
  }
  __shared__ float r0[4], r1[4];
  const int wave = tid >> 6, lane = tid & 63;
  if (lane == 0) { r0[wave] = s; r1[wave] = ss; }
  __syncthreads();
  s  = r0[0] + r0[1] + r0[2] + r0[3];
  ss = r1[0] + r1[1] + r1[2] + r1[3];
  const float mu   = s * (1.0f / C);
  const float var  = ss * (1.0f / C) - mu * mu;
  const float rstd = rsqrtf(var + 1e-5f);
  const float4 gv = ((const float4*)g)[tid];
  const float4 bv = ((const float4*)bta)[tid];
  ushort4 o;
  o.x = f2bf((v.x - mu) * rstd * gv.x + bv.x);
  o.y = f2bf((v.y - mu) * rstd * gv.y + bv.y);
  o.z = f2bf((v.z - mu) * rstd * gv.z + bv.z);
  o.w = f2bf((v.w - mu) * rstd * gv.w + bv.w);
  ((ushort4*)(out + (size_t)row * C))[tid] = o;
}

// ---------------------------------------------------------------------------
// 128x64-tile latency GEMM (round-6 verified): 512 blocks = 2 blocks/CU.
// ---------------------------------------------------------------------------
__global__ __launch_bounds__(256, 2) void gemm_lat2(
    const unsigned short* __restrict__ A, const unsigned short* __restrict__ BT,
    float* __restrict__ Cout, const float* __restrict__ bias,
    const float* __restrict__ resid, int M, int N, int K) {
  __shared__ __align__(16) unsigned short As[3][8192];
  __shared__ __align__(16) unsigned short Bs[3][4096];
  const int tid = threadIdx.x;
  const int lane = tid & 63, wave = tid >> 6;
  const int wm = wave >> 1, wn = wave & 1;
  const int lr = lane & 15, lg = lane >> 4;

  const int nwg = gridDim.x;
  const int cpx = nwg >> 3;
  const int swz = ((int)blockIdx.x & 7) * cpx + ((int)blockIdx.x >> 3);
  const int Nt = N >> 6;
  const int g4 = swz / (4 * Nt);
  const int rem = swz - g4 * 4 * Nt;
  const int m0 = (g4 * 4 + (rem & 3)) << 7;
  const int n0 = (rem >> 2) << 6;

  const int srow = tid >> 3;
  const int sc = ((tid & 7) ^ (srow & 7)) << 3;
  const unsigned short* Ag = A + (size_t)(m0 + srow) * K + sc;
  const unsigned short* Bg = BT + (size_t)(n0 + srow) * K + sc;
  const size_t rskip = (size_t)32 * K;

  f32x4 acc[4][2] = {};
  const int nkt = K >> 6;

#define STG(T, B)                                                          \
  {                                                                        \
    const int kt_ = (T) << 6;                                              \
    _Pragma("unroll")                                                      \
    for (int j = 0; j < 4; ++j)                                            \
      async16(Ag + kt_ + (size_t)j * rskip, &As[B][j * 2048 + tid * 8]);   \
    async16(Bg + kt_, &Bs[B][tid * 8]);                                    \
    async16(Bg + kt_ + rskip, &Bs[B][2048 + tid * 8]);                     \
  }

  STG(0, 0);
  STG(1, 1);

  for (int t = 0; t < nkt; ++t) {
    const int buf = t % 3;
    if (t + 1 < nkt) asm volatile("s_waitcnt vmcnt(6)" ::: "memory");
    else             asm volatile("s_waitcnt vmcnt(0)" ::: "memory");
    block_barrier();
    if (t + 2 < nkt) {
      int sb = buf + 2; if (sb >= 3) sb -= 3;
      STG(t + 2, sb);
    }
#pragma unroll
    for (int kh = 0; kh < 2; ++kh) {
      const int kc = ((kh * 4 + lg) ^ (lr & 7)) << 3;
      bf16x8 afr[4], bfr[2];
#pragma unroll
      for (int fm = 0; fm < 4; fm++)
        afr[fm] = *(const bf16x8*)&As[buf][(wm * 64 + fm * 16 + lr) * 64 + kc];
#pragma unroll
      for (int fn = 0; fn < 2; fn++)
        bfr[fn] = *(const bf16x8*)&Bs[buf][(wn * 32 + fn * 16 + lr) * 64 + kc];
#pragma unroll
      for (int fm = 0; fm < 4; fm++)
#pragma unroll
        for (int fn = 0; fn < 2; fn++)
          acc[fm][fn] = __builtin_amdgcn_mfma_f32_16x16x32_bf16(
              afr[fm], bfr[fn], acc[fm][fn], 0, 0, 0);
    }
  }
#undef STG

#pragma unroll
  for (int fn = 0; fn < 2; fn++) {
    const int col = n0 + wn * 32 + fn * 16 + lr;
    const float bv = bias[col];
#pragma unroll
    for (int fm = 0; fm < 4; fm++) {
      const int row0 = m0 + wm * 64 + fm * 16 + lg * 4;
#pragma unroll
      for (int r = 0; r < 4; r++) {
        const size_t idx = (size_t)(row0 + r) * N + col;
        Cout[idx] = acc[fm][fn][r] + bv + resid[idx];
      }
    }
  }
}

// ---------------------------------------------------------------------------
// Split-K reduce (4 planes bf16): out[i] = sum_p P[p][i] + bias + out[i].
// ---------------------------------------------------------------------------
__global__ __launch_bounds__(256) void reduce_add4(
    const unsigned short* __restrict__ p01, const unsigned short* __restrict__ p23,
    const float* __restrict__ bias, float* __restrict__ out, int n4) {
  const int stride = gridDim.x * 256;
#define BF(u) __uint_as_float(((unsigned)(u)) << 16)
  for (int i = blockIdx.x * 256 + threadIdx.x; i < n4; i += stride) {
    const ushort4 a = ((const ushort4*)p01)[i];
    const ushort4 b = ((const ushort4*)p01)[i + n4];
    const ushort4 c = ((const ushort4*)p23)[i];
    const ushort4 d = ((const ushort4*)p23)[i + n4];
    const float4 r = ((const float4*)out)[i];
    const float4 bv = ((const float4*)bias)[i & 255];
    float4 o;
    o.x = (BF(a.x) + BF(b.x)) + (BF(c.x) + BF(d.x)) + r.x + bv.x;
    o.y = (BF(a.y) + BF(b.y)) + (BF(c.y) + BF(d.y)) + r.y + bv.y;
    o.z = (BF(a.z) + BF(b.z)) + (BF(c.z) + BF(d.z)) + r.z + bv.z;
    o.w = (BF(a.w) + BF(b.w)) + (BF(c.w) + BF(d.w)) + r.w + bv.w;
    ((float4*)out)[i] = o;
  }
#undef BF
}

// ---------------------------------------------------------------------------
// 256x256 8-phase deep-pipelined GEMM, optional split-K, with COALESCED
// LDS-roundtrip epilogue.
// EPI: 2 = relu(+bias) -> bf16 ; 4 = QKV split (Q cols pre-scaled by
//      0.125*log2e) ; 5 = bf16 partial planes.
// ---------------------------------------------------------------------------
template <int EPI, int SPLITK>
__global__ __launch_bounds__(512, 2) void gemm8p(
    const unsigned short* __restrict__ A, const unsigned short* __restrict__ BT,
    void* __restrict__ Cout, void* __restrict__ Cout2,
    const float* __restrict__ bias, int M, int N, int K) {
  __shared__ __align__(16) unsigned short As[2][2][8192];
  __shared__ __align__(16) unsigned short Bs[2][2][8192];
  const int tid = threadIdx.x;
  const int lane = tid & 63;
  const int wave = tid >> 6;
  const int wm = wave >> 2, wn = wave & 3;  // 2 x 4 wave grid
  const int lr = lane & 15, lg = lane >> 4;

  const int nwg = gridDim.x;
  const int cpx = nwg >> 3;
  const int swz = ((int)blockIdx.x & 7) * cpx + ((int)blockIdx.x >> 3);
  int tile = swz, ks = 0;
  if (SPLITK > 1) {
    const int tilesPer = nwg / SPLITK;
    ks = swz / tilesPer;
    tile = swz - ks * tilesPer;
  }
  const int Ksl = K / SPLITK;
  const int k0 = ks * Ksl;
  const int Nt = N >> 8;
  const int g4 = tile / (4 * Nt);
  const int rem = tile - g4 * 4 * Nt;
  const int m0 = (g4 * 4 + (rem & 3)) << 8;
  const int n0 = (rem >> 2) << 8;

  const int srow = tid >> 2;
  const int scg = ((tid & 3) ^ ((srow >> 1) & 3)) << 3;
  const unsigned short* Ag = A + (size_t)(m0 + srow) * K + k0 + scg;
  const unsigned short* Bg = BT + (size_t)(n0 + srow) * K + k0 + scg;
  const size_t rskip = (size_t)128 * K;
  const int l8 = tid * 8;

  const int kch = (lg ^ ((lr >> 1) & 3)) << 3;

  f32x4 acc[8][4] = {};
  bf16x8 afr[4], bfr[4];
  const int nkt = Ksl >> 6;

  async16(Ag, &As[0][0][l8]);            async16(Ag + rskip, &As[0][0][l8 + 4096]);
  async16(Bg, &Bs[0][0][l8]);            async16(Bg + rskip, &Bs[0][0][l8 + 4096]);
  async16(Ag + 32, &As[0][1][l8]);       async16(Ag + 32 + rskip, &As[0][1][l8 + 4096]);
  async16(Bg + 32, &Bs[0][1][l8]);       async16(Bg + 32 + rskip, &Bs[0][1][l8 + 4096]);
  async16(Ag + 64, &As[1][0][l8]);       async16(Ag + 64 + rskip, &As[1][0][l8 + 4096]);
  async16(Bg + 64, &Bs[1][0][l8]);       async16(Bg + 64 + rskip, &Bs[1][0][l8 + 4096]);
  asm volatile("s_waitcnt vmcnt(4)" ::: "memory");
  block_barrier();

  for (int t = 0; t < nkt; ++t) {
    const int buf = t & 1, nbuf = buf ^ 1;
    const int kt1 = (t + 1) << 6, kt2 = (t + 2) << 6;
    const bool s1 = (t + 1 < nkt), s2 = (t + 2 < nkt);

    // ---- phase 1: ks=0, mh=0 ----
#pragma unroll
    for (int fm = 0; fm < 4; fm++)
      afr[fm] = *(const bf16x8*)&As[buf][0][(wm * 128 + fm * 16 + lr) * 32 + kch];
#pragma unroll
    for (int fn = 0; fn < 4; fn++)
      bfr[fn] = *(const bf16x8*)&Bs[buf][0][(wn * 64 + fn * 16 + lr) * 32 + kch];
    if (s1) {
      async16(Ag + kt1 + 32, &As[nbuf][1][l8]);
      async16(Ag + kt1 + 32 + rskip, &As[nbuf][1][l8 + 4096]);
    }
    block_barrier();
    __builtin_amdgcn_s_setprio(1);
#pragma unroll
    for (int fm = 0; fm < 4; fm++)
#pragma unroll
      for (int fn = 0; fn < 4; fn++)
        acc[fm][fn] = __builtin_amdgcn_mfma_f32_16x16x32_bf16(afr[fm], bfr[fn], acc[fm][fn], 0, 0, 0);
    __builtin_amdgcn_s_setprio(0);
    block_barrier();

    // ---- phase 2: ks=0, mh=1 ----
#pragma unroll
    for (int fm = 0; fm < 4; fm++)
      afr[fm] = *(const bf16x8*)&As[buf][0][(wm * 128 + 64 + fm * 16 + lr) * 32 + kch];
    if (s1) {
      async16(Bg + kt1 + 32, &Bs[nbuf][1][l8]);
      async16(Bg + kt1 + 32 + rskip, &Bs[nbuf][1][l8 + 4096]);
    }
    block_barrier();
    __builtin_amdgcn_s_setprio(1);
#pragma unroll
    for (int fm = 0; fm < 4; fm++)
#pragma unroll
      for (int fn = 0; fn < 4; fn++)
        acc[4 + fm][fn] = __builtin_amdgcn_mfma_f32_16x16x32_bf16(afr[fm], bfr[fn], acc[4 + fm][fn], 0, 0, 0);
    __builtin_amdgcn_s_setprio(0);
    block_barrier();

    // ---- phase 3: ks=1, mh=0 ----
#pragma unroll
    for (int fm = 0; fm < 4; fm++)
      afr[fm] = *(const bf16x8*)&As[buf][1][(wm * 128 + fm * 16 + lr) * 32 + kch];
#pragma unroll
    for (int fn = 0; fn < 4; fn++)
      bfr[fn] = *(const bf16x8*)&Bs[buf][1][(wn * 64 + fn * 16 + lr) * 32 + kch];
    if (s2) {
      async16(Ag + kt2, &As[buf][0][l8]);
      async16(Ag + kt2 + rskip, &As[buf][0][l8 + 4096]);
    }
    block_barrier();
    __builtin_amdgcn_s_setprio(1);
#pragma unroll
    for (int fm = 0; fm < 4; fm++)
#pragma unroll
      for (int fn = 0; fn < 4; fn++)
        acc[fm][fn] = __builtin_amdgcn_mfma_f32_16x16x32_bf16(afr[fm], bfr[fn], acc[fm][fn], 0, 0, 0);
    __builtin_amdgcn_s_setprio(0);
    block_barrier();

    // ---- phase 4: ks=1, mh=1 ----
#pragma unroll
    for (int fm = 0; fm < 4; fm++)
      afr[fm] = *(const bf16x8*)&As[buf][1][(wm * 128 + 64 + fm * 16 + lr) * 32 + kch];
    if (s2) {
      async16(Bg + kt2, &Bs[buf][0][l8]);
      async16(Bg + kt2 + rskip, &Bs[buf][0][l8 + 4096]);
    }
    block_barrier();
    __builtin_amdgcn_s_setprio(1);
#pragma unroll
    for (int fm = 0; fm < 4; fm++)
#pragma unroll
      for (int fn = 0; fn < 4; fn++)
        acc[4 + fm][fn] = __builtin_amdgcn_mfma_f32_16x16x32_bf16(afr[fm], bfr[fn], acc[4 + fm][fn], 0, 0, 0);
    __builtin_amdgcn_s_setprio(0);
    if (s2) asm volatile("s_waitcnt vmcnt(4)" ::: "memory");
    else    asm volatile("s_waitcnt vmcnt(0)" ::: "memory");
    block_barrier();
  }

  // ---- coalesced epilogue: acc -> LDS (bf16, XOR-swizzled) -> wide stores.
  unsigned short* wlds = &As[0][0][0] + wave * 4096;
  const bool vpath = (EPI == 4) && (n0 >= 2048);

#pragma unroll
  for (int mh = 0; mh < 2; ++mh) {
#pragma unroll
    for (int fn = 0; fn < 4; fn++) {
      const int col = n0 + wn * 64 + fn * 16 + lr;
      float bv = 0.0f;
      if (EPI == 2) bv = bias[col];
      const bool qscale = (EPI == 4) && (col < 1024);
#pragma unroll
      for (int fm = 0; fm < 4; fm++) {
#pragma unroll
        for (int r = 0; r < 4; r++) {
          float v = acc[mh * 4 + fm][fn][r];
          if (EPI == 2) v = fmaxf(v + bv, 0.0f);
          if (qscale) v *= 0.18033688011112042f;  // 0.125 * log2(e)
          wlds[(fm * 16 + lg * 4 + r) * 64 + (((fn ^ lg) << 4) | lr)] = f2bf(v);
        }
      }
    }
    asm volatile("s_waitcnt lgkmcnt(0)" ::: "memory");
    __builtin_amdgcn_sched_barrier(0);

    if (vpath) {
      const int colw = lane;
      const int fnr = colw >> 4, cin = colw & 15;
      unsigned short* dst = (unsigned short*)Cout2 +
          (size_t)(n0 - 2048 + wn * 64 + colw) * 4096 +
          (m0 + wm * 128 + mh * 64);
#pragma unroll
      for (int p = 0; p < 8; ++p) {
        unsigned short tmp[8];
#pragma unroll
        for (int j = 0; j < 8; ++j) {
          const int lrow = p * 8 + j;
          tmp[j] = wlds[lrow * 64 + (((fnr ^ ((lrow >> 2) & 3)) << 4) | cin)];
        }
        *(ushort4*)(dst + p * 8)     = *(ushort4*)&tmp[0];
        *(ushort4*)(dst + p * 8 + 4) = *(ushort4*)&tmp[4];
      }
    } else {
      const int fnr = (lane & 7) >> 1;
      const int coff = (lane & 1) << 3;
      const int gcol = n0 + wn * 64 + (lane & 7) * 8;
      const int Nst = (EPI == 4) ? 2048 : N;
      unsigned short* base;
      if (EPI == 5)
        base = (unsigned short*)(ks < 2 ? Cout : Cout2) + (size_t)(ks & 1) * M * N;
      else
        base = (unsigned short*)Cout;
#pragma unroll
      for (int p = 0; p < 8; ++p) {
        const int lrow = p * 8 + (lane >> 3);
        const bf16x8 v = *(const bf16x8*)
            &wlds[lrow * 64 + (((fnr ^ ((lrow >> 2) & 3)) << 4) | coff)];
        const size_t grow = (size_t)(m0 + wm * 128 + mh * 64 + lrow);
        *(bf16x8*)(base + grow * Nst + gcol) = v;
      }
    }
    asm volatile("s_waitcnt lgkmcnt(0)" ::: "memory");
    __builtin_amdgcn_sched_barrier(0);
  }
}

// ---------------------------------------------------------------------------
// Flash attention (causal), swapped-operand, LDS-staged K/V, double-buffered,
// exp2-domain softmax, MFMA-lsum. 1024 blocks, XCD-grouped + LPT.
// (round-15 proven structure: Ps[16][64] chunk-XOR swizzled, 40960 B LDS)
// ---------------------------------------------------------------------------
__global__ __launch_bounds__(256, 4) void attn_kernel(
    const unsigned short* __restrict__ qk, const unsigned short* __restrict__ vT,
    unsigned short* __restrict__ o) {
  const int T = 2048, C = 1024, QKS = 2048;
  const int tid = threadIdx.x;
  const int wave = tid >> 6, lane = tid & 63;
  const int lr = lane & 15, lg = lane >> 4;

  // decode XCD-grouped LPT mapping
  const int id = (int)blockIdx.x;
  const int rest = id >> 3;           // [0,128)
  const int bhHi = rest & 3;
  const int qt = 31 - (rest >> 2);    // longest first
  const int bh = (bhHi << 3) | (id & 7);
  const int b = bh >> 4, hh = bh & 15;

  const size_t rowb = (size_t)b * T * QKS;
  const int qcol = hh * 64;
  const int kcol = 1024 + hh * 64;
  const int vrow0 = hh * 64;
  const size_t bT = (size_t)b * T;
  const int swe = (lr & 7) << 3;

  __shared__ __align__(16) unsigned short Ks[2][64 * 64];
  __shared__ __align__(16) unsigned short Vs[2][64 * 64];
  __shared__ __align__(16) unsigned short Ps[4][16][64];

  const int rw = tid >> 3;
  const int c8 = ((tid & 7) ^ (rw & 7)) << 3;

  const int qbase = qt * 64 + wave * 16;
  const int trow = qbase + lr;
  const int pswz = lr & 7;   // Ps chunk XOR key

  U8 ones;
#pragma unroll
  for (int j = 0; j < 8; j++) ones.u[j] = 0x3F80;  // bf16 1.0

  U8 qf[2];
#pragma unroll
  for (int j = 0; j < 2; j++)
    qf[j].v = *(const bf16x8*)(qk + rowb + (size_t)trow * QKS + qcol + j * 32 + lg * 8);
  asm volatile("s_waitcnt vmcnt(0)" ::: "memory");

  async16(qk + rowb + (size_t)rw * QKS + kcol + c8, Ks[0] + tid * 8);
  async16(qk + rowb + (size_t)(32 + rw) * QKS + kcol + c8, Ks[0] + 2048 + tid * 8);
  async16(vT + (size_t)(vrow0 + rw) * 4096 + bT + c8, Vs[0] + tid * 8);
  async16(vT + (size_t)(vrow0 + 32 + rw) * 4096 + bT + c8, Vs[0] + 2048 + tid * 8);

  f32x4 oa[4] = {};
  f32x4 oas = {};               // lsum accumulator via ones-row MFMA
  float mrun = -1e30f;
  int cur = 0;

  for (int sb = 0; sb <= qt; ++sb) {
    if (sb < qt) {
      const int s1 = (sb + 1) * 64;
      const int nb = cur ^ 1;
      async16(qk + rowb + (size_t)(s1 + rw) * QKS + kcol + c8, Ks[nb] + tid * 8);
      async16(qk + rowb + (size_t)(s1 + 32 + rw) * QKS + kcol + c8, Ks[nb] + 2048 + tid * 8);
      async16(vT + (size_t)(vrow0 + rw) * 4096 + bT + s1 + c8, Vs[nb] + tid * 8);
      async16(vT + (size_t)(vrow0 + 32 + rw) * 4096 + bT + s1 + c8, Vs[nb] + 2048 + tid * 8);
      asm volatile("s_waitcnt vmcnt(4)" ::: "memory");
    } else {
      asm volatile("s_waitcnt vmcnt(0)" ::: "memory");
    }
    block_barrier();

    const unsigned short* Kc = Ks[cur];
    const unsigned short* Vc = Vs[cur];
    const int s0 = sb * 64;

    f32x4 sa[4] = {};
    __builtin_amdgcn_s_setprio(1);
#pragma unroll
    for (int j = 0; j < 2; j++) {
#pragma unroll
      for (int mf = 0; mf < 4; mf++) {
        U8 kf;
        kf.v = *(const bf16x8*)(Kc + (mf * 16 + lr) * 64 + ((j * 32 + lg * 8) ^ swe));
        sa[mf] = __builtin_amdgcn_mfma_f32_16x16x32_bf16(kf.v, qf[j].v, sa[mf], 0, 0, 0);
      }
    }
    __builtin_amdgcn_s_setprio(0);
    float sv[16];
#pragma unroll
    for (int mf = 0; mf < 4; mf++)
#pragma unroll
      for (int r = 0; r < 4; r++) sv[mf * 4 + r] = sa[mf][r];  // log2-scaled

    if (sb == qt) {
#pragma unroll
      for (int mf = 0; mf < 4; mf++)
#pragma unroll
        for (int r = 0; r < 4; r++)
          if (s0 + mf * 16 + lg * 4 + r > trow) sv[mf * 4 + r] = -1e30f;
    }

    // max over 16 (max3-shaped) + 2 cross-lane steps
    const float g0 = fmaxf(fmaxf(sv[0], sv[1]), sv[2]);
    const float g1 = fmaxf(fmaxf(sv[3], sv[4]), sv[5]);
    const float g2 = fmaxf(fmaxf(sv[6], sv[7]), sv[8]);
    const float g3 = fmaxf(fmaxf(sv[9], sv[10]), sv[11]);
    const float g4 = fmaxf(fmaxf(sv[12], sv[13]), sv[14]);
    float tm = fmaxf(fmaxf(fmaxf(fmaxf(g0, g1), g2), fmaxf(g3, g4)), sv[15]);
    tm = fmaxf(tm, __shfl_xor(tm, 16));
    tm = fmaxf(tm, __shfl_xor(tm, 32));

    if (!__all(tm <= mrun + 8.0f)) {  // defer-max (log2 units)
      const float mn = fmaxf(mrun, tm);
      const float corr = __builtin_amdgcn_exp2f(mrun - mn);
#pragma unroll
      for (int c = 0; c < 4; c++)
#pragma unroll
        for (int r = 0; r < 4; r++) oa[c][r] *= corr;
#pragma unroll
      for (int r = 0; r < 4; r++) oas[r] *= corr;
      mrun = mn;
    }

#pragma unroll
    for (int i = 0; i < 16; i++)
      sv[i] = __builtin_amdgcn_exp2f(sv[i] - mrun);

    // P -> LDS, chunk-XOR swizzled (chunk = 8 elems; involution by lr&7)
#pragma unroll
    for (int mf = 0; mf < 4; mf++) {
      ushort4 w;
      w.x = f2bf(sv[mf * 4 + 0]);
      w.y = f2bf(sv[mf * 4 + 1]);
      w.z = f2bf(sv[mf * 4 + 2]);
      w.w = f2bf(sv[mf * 4 + 3]);
      const int wchunk = (mf * 2 + (lg >> 1)) ^ pswz;
      *(ushort4*)&Ps[wave][lr][wchunk * 8 + (lg & 1) * 4] = w;
    }
    asm volatile("" ::: "memory");
    U8 pb[2];
    pb[0].v = *(const bf16x8*)&Ps[wave][lr][(lg ^ pswz) * 8];
    pb[1].v = *(const bf16x8*)&Ps[wave][lr][((4 + lg) ^ pswz) * 8];
    asm volatile("" ::: "memory");

    __builtin_amdgcn_s_setprio(1);
#pragma unroll
    for (int c = 0; c < 4; c++) {
#pragma unroll
      for (int ks = 0; ks < 2; ks++) {
        U8 vf;
        vf.v = *(const bf16x8*)(Vc + (c * 16 + lr) * 64 + ((ks * 32 + lg * 8) ^ swe));
        oa[c] = __builtin_amdgcn_mfma_f32_16x16x32_bf16(vf.v, pb[ks].v, oa[c], 0, 0, 0);
      }
    }
    // lsum contribution: ones-row MFMA (column sums of P)
    oas = __builtin_amdgcn_mfma_f32_16x16x32_bf16(ones.v, pb[0].v, oas, 0, 0, 0);
    oas = __builtin_amdgcn_mfma_f32_16x16x32_bf16(ones.v, pb[1].v, oas, 0, 0, 0);
    __builtin_amdgcn_s_setprio(0);

    block_barrier();
    cur ^= 1;
  }

  const float inv = 1.0f / oas[0];
#pragma unroll
  for (int c = 0; c < 4; c++) {
    ushort4 ov;
    ov.x = f2bf(oa[c][0] * inv);
    ov.y = f2bf(oa[c][1] * inv);
    ov.z = f2bf(oa[c][2] * inv);
    ov.w = f2bf(oa[c][3] * inv);
    *(ushort4*)(o + (size_t)(bT + trow) * C + hh * 64 + c * 16 + lg * 4) = ov;
  }
}

// ---------------------------------------------------------------------------
// Orchestration.  Workspace lifetimes (80 MB):
//   0-6 WqkvT (dead after QKV) | 6-8 WpT (dead after proj) | 8-16 W1T (dead
//   after FFN1) | 16-24 W2T (thru FFN2) | 24-32 h (dead after QKV) |
//   32-48 qkb, 48-56 vTb (dead after attn) | 56-64 att -> h2 |
//   24-56 ff1 after FFN1 | x1 = d_out | FFN2 bf16 partials: 0-16 & 64-80.
// ---------------------------------------------------------------------------
extern "C" void kernel_launch(void* const* d_in, const int* in_sizes, int n_in,
                              void* d_out, int out_size, void* d_ws, size_t ws_size,
                              hipStream_t stream) {
  (void)in_sizes; (void)n_in; (void)out_size; (void)ws_size;
  const int T = 2048, C = 1024, M = 2 * T, C4 = 4 * C;

  const float* x     = (const float*)d_in[0];
  const float* Wq    = (const float*)d_in[1];
  const float* Wk    = (const float*)d_in[2];
  const float* Wv    = (const float*)d_in[3];
  const float* Wproj = (const float*)d_in[4];
  const float* bproj = (const float*)d_in[5];
  const float* W1    = (const float*)d_in[6];
  const float* b1    = (const float*)d_in[7];
  const float* W2    = (const float*)d_in[8];
  const float* b2    = (const float*)d_in[9];
  const float* ln1g  = (const float*)d_in[10];
  const float* ln1b  = (const float*)d_in[11];
  const float* ln2g  = (const float*)d_in[12];
  const float* ln2b  = (const float*)d_in[13];
  float* out = (float*)d_out;

  char* ws = (char*)d_ws;
  const size_t MBy = (size_t)1 << 20;
  unsigned short* WqkvT = (unsigned short*)(ws + 0 * MBy);
  unsigned short* WpT = (unsigned short*)(ws + 6 * MBy);
  unsigned short* W1T = (unsigned short*)(ws + 8 * MBy);
  unsigned short* W2T = (unsigned short*)(ws + 16 * MBy);
  unsigned short* h   = (unsigned short*)(ws + 24 * MBy);
  unsigned short* qkb = (unsigned short*)(ws + 32 * MBy);
  unsigned short* vTb = (unsigned short*)(ws + 48 * MBy);
  unsigned short* att = (unsigned short*)(ws + 56 * MBy);
  float* x1 = out;                                    // x1 lives in d_out
  unsigned short* h2  = att;
  unsigned short* ff1 = h;
  unsigned short* ffP01 = (unsigned short*)(ws + 0 * MBy);   // planes 0,1
  unsigned short* ffP23 = (unsigned short*)(ws + 64 * MBy);  // planes 2,3

  const dim3 tb(32, 8);
  transpose_qkv<<<dim3(2, 32, 48), tb, 0, stream>>>(Wq, Wk, Wv, WqkvT);
  // merged Wproj/W1/W2 transpose: 1024 + 4096 + 4096 = 9216 tiles
  transpose_rest<<<9216, tb, 0, stream>>>(Wproj, W1, W2, WpT, W1T, W2T);

  ln_kernel<<<M, 256, 0, stream>>>(x, ln1g, ln1b, h);

  // Fused QKV (8-phase 256^2): Q cols pre-scaled by 0.125*log2e
  gemm8p<4, 1><<<192, 512, 0, stream>>>(h, WqkvT, qkb, vTb, nullptr, M, 3072, C);

  // attn: 1024 blocks, XCD-grouped + LPT (round-15 proven kernel)
  attn_kernel<<<1024, 256, 0, stream>>>(qkb, vTb, att);

  // proj (+bproj +x) -> x1 (d_out)
  gemm_lat2<<<512, 256, 0, stream>>>(att, WpT, x1, bproj, x, M, C, C);

  ln_kernel<<<M, 256, 0, stream>>>(x1, ln2g, ln2b, h2);

  // FFN1 (8-phase 256^2): relu(h2 @ W1 + b1) -> bf16
  gemm8p<2, 1><<<256, 512, 0, stream>>>(h2, W1T, ff1, nullptr, b1, M, C4, C);

  // FFN2: split-K=4 8-phase partials (bf16) + fused reduce (+b2 +x1 in-place)
  gemm8p<5, 4><<<256, 512, 0, stream>>>(ff1, W2T, ffP01, ffP23, nullptr, M, C, C4);
  reduce_add4<<<2048, 256, 0, stream>>>(ffP01, ffP23, b2, out, M * C / 4);
}

// Round 19
// 212.702 us; speedup vs baseline: 1.0458x; 1.0016x over previous
//
#include <hip/hip_runtime.h>

// ---------------------------------------------------------------------------
// Types / helpers
// ---------------------------------------------------------------------------
typedef __bf16 bf16x8 __attribute__((ext_vector_type(8)));
typedef float  f32x4  __attribute__((ext_vector_type(4)));

union U8 { bf16x8 v; __bf16 e[8]; unsigned short u[8]; };

// Native HW conversion (v_cvt_*_bf16), RNE.
__device__ __forceinline__ unsigned short f2bf(float f) {
  union { __bf16 b; unsigned short u; } c;
  c.b = (__bf16)f;
  return c.u;
}

__device__ __forceinline__ void async16(const void* g, void* l) {
  __builtin_amdgcn_global_load_lds(
      (__attribute__((address_space(1))) void*)(g),
      (__attribute__((address_space(3))) void*)(l), 16, 0, 0);
}

__device__ __forceinline__ void block_barrier() {
  asm volatile("" ::: "memory");
  __builtin_amdgcn_sched_barrier(0);
  __builtin_amdgcn_s_barrier();
  __builtin_amdgcn_sched_barrier(0);
  asm volatile("" ::: "memory");
}

// ---------------------------------------------------------------------------
// Merged Wq/Wk/Wv transpose: z in [0,48), source picked by z/16.
// ---------------------------------------------------------------------------
__global__ __launch_bounds__(256) void transpose_qkv(
    const float* __restrict__ Wq, const float* __restrict__ Wk,
    const float* __restrict__ Wv, unsigned short* __restrict__ out) {
  __shared__ float tile[32][33];
  const int z = blockIdx.z;
  const float* src = (z < 16) ? Wq : (z < 32 ? Wk : Wv);
  const int batch = z & 15;
  const int R = 1024, Cc = 64;
  const float* ip = src + (size_t)batch * R * Cc;
  unsigned short* op = out + (size_t)z * R * Cc;
  const int c0 = blockIdx.x * 32, r0 = blockIdx.y * 32;
  const int tx = threadIdx.x, ty = threadIdx.y;
#pragma unroll
  for (int i = 0; i < 32; i += 8)
    tile[ty + i][tx] = ip[(size_t)(r0 + ty + i) * Cc + c0 + tx];
  __syncthreads();
#pragma unroll
  for (int i = 0; i < 32; i += 8)
    op[(size_t)(c0 + ty + i) * R + r0 + tx] = f2bf(tile[tx][ty + i]);
}

// ---------------------------------------------------------------------------
// Merged Wproj/W1/W2 transpose: one dispatch, flat block-id decode.
// ---------------------------------------------------------------------------
__global__ __launch_bounds__(256) void transpose_rest(
    const float* __restrict__ Wproj, const float* __restrict__ W1,
    const float* __restrict__ W2, unsigned short* __restrict__ WpT,
    unsigned short* __restrict__ W1T, unsigned short* __restrict__ W2T) {
  __shared__ float tile[32][33];
  const int id = (int)blockIdx.x;
  const float* ip;
  unsigned short* op;
  int R, Cc, bx, by;
  if (id < 1024) {
    ip = Wproj; op = WpT; R = 1024; Cc = 1024;
    bx = id & 31; by = id >> 5;
  } else if (id < 1024 + 4096) {
    const int t = id - 1024;
    ip = W1; op = W1T; R = 1024; Cc = 4096;
    bx = t & 127; by = t >> 7;
  } else {
    const int t = id - 5120;
    ip = W2; op = W2T; R = 4096; Cc = 1024;
    bx = t & 31; by = t >> 5;
  }
  const int c0 = bx * 32, r0 = by * 32;
  const int tx = threadIdx.x, ty = threadIdx.y;  // 32 x 8
#pragma unroll
  for (int i = 0; i < 32; i += 8)
    tile[ty + i][tx] = ip[(size_t)(r0 + ty + i) * Cc + c0 + tx];
  __syncthreads();
#pragma unroll
  for (int i = 0; i < 32; i += 8)
    op[(size_t)(c0 + ty + i) * R + r0 + tx] = f2bf(tile[tx][ty + i]);
}

// ---------------------------------------------------------------------------
// LayerNorm over rows of 1024, fp32 in -> bf16 out.
// ---------------------------------------------------------------------------
__global__ __launch_bounds__(256) void ln_kernel(
    const float* __restrict__ x, const float* __restrict__ g,
    const float* __restrict__ bta, unsigned short* __restrict__ out) {
  const int C = 1024;
  const int row = blockIdx.x, tid = threadIdx.x;
  const float4 v = ((const float4*)(x + (size_t)row * C))[tid];
  float s  = v.x + v.y + v.z + v.w;
  float ss = v.x * v.x + v.y * v.y + v.z * v.z + v.w * v.w;
#pragma unroll
  for (int off = 32; off > 0; off >>= 1) {
    s  += __shfl_down(s, off);
    ss += __shfl_down(ss, off);
  }
  __shared__ float r0[4], r1[4];
  const int wave = tid >> 6, lane = tid & 63;
  if (lane == 0) { r0[wave] = s; r1[wave] = ss; }
  __syncthreads();
  s  = r0[0] + r0[1] + r0[2] + r0[3];
  ss = r1[0] + r1[1] + r1[2] + r1[3];
  const float mu   = s * (1.0f / C);
  const float var  = ss * (1.0f / C) - mu * mu;
  const float rstd = rsqrtf(var + 1e-5f);
  const float4 gv = ((const float4*)g)[tid];
  const float4 bv = ((const float4*)bta)[tid];
  ushort4 o;
  o.x = f2bf((v.x - mu) * rstd * gv.x + bv.x);
  o.y = f2bf((v.y - mu) * rstd * gv.y + bv.y);
  o.z = f2bf((v.z - mu) * rstd * gv.z + bv.z);
  o.w = f2bf((v.w - mu) * rstd * gv.w + bv.w);
  ((ushort4*)(out + (size_t)row * C))[tid] = o;
}

// ---------------------------------------------------------------------------
// 128x64-tile latency GEMM (round-6 verified): 512 blocks = 2 blocks/CU.
// ---------------------------------------------------------------------------
__global__ __launch_bounds__(256, 2) void gemm_lat2(
    const unsigned short* __restrict__ A, const unsigned short* __restrict__ BT,
    float* __restrict__ Cout, const float* __restrict__ bias,
    const float* __restrict__ resid, int M, int N, int K) {
  __shared__ __align__(16) unsigned short As[3][8192];
  __shared__ __align__(16) unsigned short Bs[3][4096];
  const int tid = threadIdx.x;
  const int lane = tid & 63, wave = tid >> 6;
  const int wm = wave >> 1, wn = wave & 1;
  const int lr = lane & 15, lg = lane >> 4;

  const int nwg = gridDim.x;
  const int cpx = nwg >> 3;
  const int swz = ((int)blockIdx.x & 7) * cpx + ((int)blockIdx.x >> 3);
  const int Nt = N >> 6;
  const int g4 = swz / (4 * Nt);
  const int rem = swz - g4 * 4 * Nt;
  const int m0 = (g4 * 4 + (rem & 3)) << 7;
  const int n0 = (rem >> 2) << 6;

  const int srow = tid >> 3;
  const int sc = ((tid & 7) ^ (srow & 7)) << 3;
  const unsigned short* Ag = A + (size_t)(m0 + srow) * K + sc;
  const unsigned short* Bg = BT + (size_t)(n0 + srow) * K + sc;
  const size_t rskip = (size_t)32 * K;

  f32x4 acc[4][2] = {};
  const int nkt = K >> 6;

#define STG(T, B)                                                          \
  {                                                                        \
    const int kt_ = (T) << 6;                                              \
    _Pragma("unroll")                                                      \
    for (int j = 0; j < 4; ++j)                                            \
      async16(Ag + kt_ + (size_t)j * rskip, &As[B][j * 2048 + tid * 8]);   \
    async16(Bg + kt_, &Bs[B][tid * 8]);                                    \
    async16(Bg + kt_ + rskip, &Bs[B][2048 + tid * 8]);                     \
  }

  STG(0, 0);
  STG(1, 1);

  for (int t = 0; t < nkt; ++t) {
    const int buf = t % 3;
    if (t + 1 < nkt) asm volatile("s_waitcnt vmcnt(6)" ::: "memory");
    else             asm volatile("s_waitcnt vmcnt(0)" ::: "memory");
    block_barrier();
    if (t + 2 < nkt) {
      int sb = buf + 2; if (sb >= 3) sb -= 3;
      STG(t + 2, sb);
    }
#pragma unroll
    for (int kh = 0; kh < 2; ++kh) {
      const int kc = ((kh * 4 + lg) ^ (lr & 7)) << 3;
      bf16x8 afr[4], bfr[2];
#pragma unroll
      for (int fm = 0; fm < 4; fm++)
        afr[fm] = *(const bf16x8*)&As[buf][(wm * 64 + fm * 16 + lr) * 64 + kc];
#pragma unroll
      for (int fn = 0; fn < 2; fn++)
        bfr[fn] = *(const bf16x8*)&Bs[buf][(wn * 32 + fn * 16 + lr) * 64 + kc];
#pragma unroll
      for (int fm = 0; fm < 4; fm++)
#pragma unroll
        for (int fn = 0; fn < 2; fn++)
          acc[fm][fn] = __builtin_amdgcn_mfma_f32_16x16x32_bf16(
              afr[fm], bfr[fn], acc[fm][fn], 0, 0, 0);
    }
  }
#undef STG

#pragma unroll
  for (int fn = 0; fn < 2; fn++) {
    const int col = n0 + wn * 32 + fn * 16 + lr;
    const float bv = bias[col];
#pragma unroll
    for (int fm = 0; fm < 4; fm++) {
      const int row0 = m0 + wm * 64 + fm * 16 + lg * 4;
#pragma unroll
      for (int r = 0; r < 4; r++) {
        const size_t idx = (size_t)(row0 + r) * N + col;
        Cout[idx] = acc[fm][fn][r] + bv + resid[idx];
      }
    }
  }
}

// ---------------------------------------------------------------------------
// Split-K reduce (4 planes bf16): out[i] = sum_p P[p][i] + bias + out[i].
// ---------------------------------------------------------------------------
__global__ __launch_bounds__(256) void reduce_add4(
    const unsigned short* __restrict__ p01, const unsigned short* __restrict__ p23,
    const float* __restrict__ bias, float* __restrict__ out, int n4) {
  const int stride = gridDim.x * 256;
#define BF(u) __uint_as_float(((unsigned)(u)) << 16)
  for (int i = blockIdx.x * 256 + threadIdx.x; i < n4; i += stride) {
    const ushort4 a = ((const ushort4*)p01)[i];
    const ushort4 b = ((const ushort4*)p01)[i + n4];
    const ushort4 c = ((const ushort4*)p23)[i];
    const ushort4 d = ((const ushort4*)p23)[i + n4];
    const float4 r = ((const float4*)out)[i];
    const float4 bv = ((const float4*)bias)[i & 255];
    float4 o;
    o.x = (BF(a.x) + BF(b.x)) + (BF(c.x) + BF(d.x)) + r.x + bv.x;
    o.y = (BF(a.y) + BF(b.y)) + (BF(c.y) + BF(d.y)) + r.y + bv.y;
    o.z = (BF(a.z) + BF(b.z)) + (BF(c.z) + BF(d.z)) + r.z + bv.z;
    o.w = (BF(a.w) + BF(b.w)) + (BF(c.w) + BF(d.w)) + r.w + bv.w;
    ((float4*)out)[i] = o;
  }
#undef BF
}

// ---------------------------------------------------------------------------
// 256x256 8-phase deep-pipelined GEMM, optional split-K, with COALESCED
// LDS-roundtrip epilogue.
// EPI: 2 = relu(+bias) -> bf16 ; 4 = QKV split (Q cols pre-scaled by
//      0.125*log2e) ; 5 = bf16 partial planes.
// ---------------------------------------------------------------------------
template <int EPI, int SPLITK>
__global__ __launch_bounds__(512, 2) void gemm8p(
    const unsigned short* __restrict__ A, const unsigned short* __restrict__ BT,
    void* __restrict__ Cout, void* __restrict__ Cout2,
    const float* __restrict__ bias, int M, int N, int K) {
  __shared__ __align__(16) unsigned short As[2][2][8192];
  __shared__ __align__(16) unsigned short Bs[2][2][8192];
  const int tid = threadIdx.x;
  const int lane = tid & 63;
  const int wave = tid >> 6;
  const int wm = wave >> 2, wn = wave & 3;  // 2 x 4 wave grid
  const int lr = lane & 15, lg = lane >> 4;

  const int nwg = gridDim.x;
  const int cpx = nwg >> 3;
  const int swz = ((int)blockIdx.x & 7) * cpx + ((int)blockIdx.x >> 3);
  int tile = swz, ks = 0;
  if (SPLITK > 1) {
    const int tilesPer = nwg / SPLITK;
    ks = swz / tilesPer;
    tile = swz - ks * tilesPer;
  }
  const int Ksl = K / SPLITK;
  const int k0 = ks * Ksl;
  const int Nt = N >> 8;
  const int g4 = tile / (4 * Nt);
  const int rem = tile - g4 * 4 * Nt;
  const int m0 = (g4 * 4 + (rem & 3)) << 8;
  const int n0 = (rem >> 2) << 8;

  const int srow = tid >> 2;
  const int scg = ((tid & 3) ^ ((srow >> 1) & 3)) << 3;
  const unsigned short* Ag = A + (size_t)(m0 + srow) * K + k0 + scg;
  const unsigned short* Bg = BT + (size_t)(n0 + srow) * K + k0 + scg;
  const size_t rskip = (size_t)128 * K;
  const int l8 = tid * 8;

  const int kch = (lg ^ ((lr >> 1) & 3)) << 3;

  f32x4 acc[8][4] = {};
  bf16x8 afr[4], bfr[4];
  const int nkt = Ksl >> 6;

  async16(Ag, &As[0][0][l8]);            async16(Ag + rskip, &As[0][0][l8 + 4096]);
  async16(Bg, &Bs[0][0][l8]);            async16(Bg + rskip, &Bs[0][0][l8 + 4096]);
  async16(Ag + 32, &As[0][1][l8]);       async16(Ag + 32 + rskip, &As[0][1][l8 + 4096]);
  async16(Bg + 32, &Bs[0][1][l8]);       async16(Bg + 32 + rskip, &Bs[0][1][l8 + 4096]);
  async16(Ag + 64, &As[1][0][l8]);       async16(Ag + 64 + rskip, &As[1][0][l8 + 4096]);
  async16(Bg + 64, &Bs[1][0][l8]);       async16(Bg + 64 + rskip, &Bs[1][0][l8 + 4096]);
  asm volatile("s_waitcnt vmcnt(4)" ::: "memory");
  block_barrier();

  for (int t = 0; t < nkt; ++t) {
    const int buf = t & 1, nbuf = buf ^ 1;
    const int kt1 = (t + 1) << 6, kt2 = (t + 2) << 6;
    const bool s1 = (t + 1 < nkt), s2 = (t + 2 < nkt);

    // ---- phase 1: ks=0, mh=0 ----
#pragma unroll
    for (int fm = 0; fm < 4; fm++)
      afr[fm] = *(const bf16x8*)&As[buf][0][(wm * 128 + fm * 16 + lr) * 32 + kch];
#pragma unroll
    for (int fn = 0; fn < 4; fn++)
      bfr[fn] = *(const bf16x8*)&Bs[buf][0][(wn * 64 + fn * 16 + lr) * 32 + kch];
    if (s1) {
      async16(Ag + kt1 + 32, &As[nbuf][1][l8]);
      async16(Ag + kt1 + 32 + rskip, &As[nbuf][1][l8 + 4096]);
    }
    block_barrier();
    __builtin_amdgcn_s_setprio(1);
#pragma unroll
    for (int fm = 0; fm < 4; fm++)
#pragma unroll
      for (int fn = 0; fn < 4; fn++)
        acc[fm][fn] = __builtin_amdgcn_mfma_f32_16x16x32_bf16(afr[fm], bfr[fn], acc[fm][fn], 0, 0, 0);
    __builtin_amdgcn_s_setprio(0);
    block_barrier();

    // ---- phase 2: ks=0, mh=1 ----
#pragma unroll
    for (int fm = 0; fm < 4; fm++)
      afr[fm] = *(const bf16x8*)&As[buf][0][(wm * 128 + 64 + fm * 16 + lr) * 32 + kch];
    if (s1) {
      async16(Bg + kt1 + 32, &Bs[nbuf][1][l8]);
      async16(Bg + kt1 + 32 + rskip, &Bs[nbuf][1][l8 + 4096]);
    }
    block_barrier();
    __builtin_amdgcn_s_setprio(1);
#pragma unroll
    for (int fm = 0; fm < 4; fm++)
#pragma unroll
      for (int fn = 0; fn < 4; fn++)
        acc[4 + fm][fn] = __builtin_amdgcn_mfma_f32_16x16x32_bf16(afr[fm], bfr[fn], acc[4 + fm][fn], 0, 0, 0);
    __builtin_amdgcn_s_setprio(0);
    block_barrier();

    // ---- phase 3: ks=1, mh=0 ----
#pragma unroll
    for (int fm = 0; fm < 4; fm++)
      afr[fm] = *(const bf16x8*)&As[buf][1][(wm * 128 + fm * 16 + lr) * 32 + kch];
#pragma unroll
    for (int fn = 0; fn < 4; fn++)
      bfr[fn] = *(const bf16x8*)&Bs[buf][1][(wn * 64 + fn * 16 + lr) * 32 + kch];
    if (s2) {
      async16(Ag + kt2, &As[buf][0][l8]);
      async16(Ag + kt2 + rskip, &As[buf][0][l8 + 4096]);
    }
    block_barrier();
    __builtin_amdgcn_s_setprio(1);
#pragma unroll
    for (int fm = 0; fm < 4; fm++)
#pragma unroll
      for (int fn = 0; fn < 4; fn++)
        acc[fm][fn] = __builtin_amdgcn_mfma_f32_16x16x32_bf16(afr[fm], bfr[fn], acc[fm][fn], 0, 0, 0);
    __builtin_amdgcn_s_setprio(0);
    block_barrier();

    // ---- phase 4: ks=1, mh=1 ----
#pragma unroll
    for (int fm = 0; fm < 4; fm++)
      afr[fm] = *(const bf16x8*)&As[buf][1][(wm * 128 + 64 + fm * 16 + lr) * 32 + kch];
    if (s2) {
      async16(Bg + kt2, &Bs[buf][0][l8]);
      async16(Bg + kt2 + rskip, &Bs[buf][0][l8 + 4096]);
    }
    block_barrier();
    __builtin_amdgcn_s_setprio(1);
#pragma unroll
    for (int fm = 0; fm < 4; fm++)
#pragma unroll
      for (int fn = 0; fn < 4; fn++)
        acc[4 + fm][fn] = __builtin_amdgcn_mfma_f32_16x16x32_bf16(afr[fm], bfr[fn], acc[4 + fm][fn], 0, 0, 0);
    __builtin_amdgcn_s_setprio(0);
    if (s2) asm volatile("s_waitcnt vmcnt(4)" ::: "memory");
    else    asm volatile("s_waitcnt vmcnt(0)" ::: "memory");
    block_barrier();
  }

  // ---- coalesced epilogue: acc -> LDS (bf16, XOR-swizzled) -> wide stores.
  unsigned short* wlds = &As[0][0][0] + wave * 4096;
  const bool vpath = (EPI == 4) && (n0 >= 2048);

#pragma unroll
  for (int mh = 0; mh < 2; ++mh) {
#pragma unroll
    for (int fn = 0; fn < 4; fn++) {
      const int col = n0 + wn * 64 + fn * 16 + lr;
      float bv = 0.0f;
      if (EPI == 2) bv = bias[col];
      const bool qscale = (EPI == 4) && (col < 1024);
#pragma unroll
      for (int fm = 0; fm < 4; fm++) {
#pragma unroll
        for (int r = 0; r < 4; r++) {
          float v = acc[mh * 4 + fm][fn][r];
          if (EPI == 2) v = fmaxf(v + bv, 0.0f);
          if (qscale) v *= 0.18033688011112042f;  // 0.125 * log2(e)
          wlds[(fm * 16 + lg * 4 + r) * 64 + (((fn ^ lg) << 4) | lr)] = f2bf(v);
        }
      }
    }
    asm volatile("s_waitcnt lgkmcnt(0)" ::: "memory");
    __builtin_amdgcn_sched_barrier(0);

    if (vpath) {
      const int colw = lane;
      const int fnr = colw >> 4, cin = colw & 15;
      unsigned short* dst = (unsigned short*)Cout2 +
          (size_t)(n0 - 2048 + wn * 64 + colw) * 4096 +
          (m0 + wm * 128 + mh * 64);
#pragma unroll
      for (int p = 0; p < 8; ++p) {
        unsigned short tmp[8];
#pragma unroll
        for (int j = 0; j < 8; ++j) {
          const int lrow = p * 8 + j;
          tmp[j] = wlds[lrow * 64 + (((fnr ^ ((lrow >> 2) & 3)) << 4) | cin)];
        }
        *(ushort4*)(dst + p * 8)     = *(ushort4*)&tmp[0];
        *(ushort4*)(dst + p * 8 + 4) = *(ushort4*)&tmp[4];
      }
    } else {
      const int fnr = (lane & 7) >> 1;
      const int coff = (lane & 1) << 3;
      const int gcol = n0 + wn * 64 + (lane & 7) * 8;
      const int Nst = (EPI == 4) ? 2048 : N;
      unsigned short* base;
      if (EPI == 5)
        base = (unsigned short*)(ks < 2 ? Cout : Cout2) + (size_t)(ks & 1) * M * N;
      else
        base = (unsigned short*)Cout;
#pragma unroll
      for (int p = 0; p < 8; ++p) {
        const int lrow = p * 8 + (lane >> 3);
        const bf16x8 v = *(const bf16x8*)
            &wlds[lrow * 64 + (((fnr ^ ((lrow >> 2) & 3)) << 4) | coff)];
        const size_t grow = (size_t)(m0 + wm * 128 + mh * 64 + lrow);
        *(bf16x8*)(base + grow * Nst + gcol) = v;
      }
    }
    asm volatile("s_waitcnt lgkmcnt(0)" ::: "memory");
    __builtin_amdgcn_sched_barrier(0);
  }
}

// ---------------------------------------------------------------------------
// Flash attention (causal), swapped-operand, LDS-staged K/V, double-buffered,
// exp2-domain softmax, MFMA-lsum. 1024 blocks, XCD-grouped + LPT.
// (round-15/17 proven structure: Ps[16][64] chunk-XOR swizzled, 40960 B LDS,
// running max + defer-max THR=8)
// ---------------------------------------------------------------------------
__global__ __launch_bounds__(256, 4) void attn_kernel(
    const unsigned short* __restrict__ qk, const unsigned short* __restrict__ vT,
    unsigned short* __restrict__ o) {
  const int T = 2048, C = 1024, QKS = 2048;
  const int tid = threadIdx.x;
  const int wave = tid >> 6, lane = tid & 63;
  const int lr = lane & 15, lg = lane >> 4;

  // decode XCD-grouped LPT mapping
  const int id = (int)blockIdx.x;
  const int rest = id >> 3;           // [0,128)
  const int bhHi = rest & 3;
  const int qt = 31 - (rest >> 2);    // longest first
  const int bh = (bhHi << 3) | (id & 7);
  const int b = bh >> 4, hh = bh & 15;

  const size_t rowb = (size_t)b * T * QKS;
  const int qcol = hh * 64;
  const int kcol = 1024 + hh * 64;
  const int vrow0 = hh * 64;
  const size_t bT = (size_t)b * T;
  const int swe = (lr & 7) << 3;

  __shared__ __align__(16) unsigned short Ks[2][64 * 64];
  __shared__ __align__(16) unsigned short Vs[2][64 * 64];
  __shared__ __align__(16) unsigned short Ps[4][16][64];

  const int rw = tid >> 3;
  const int c8 = ((tid & 7) ^ (rw & 7)) << 3;

  const int qbase = qt * 64 + wave * 16;
  const int trow = qbase + lr;
  const int pswz = lr & 7;   // Ps chunk XOR key

  U8 ones;
#pragma unroll
  for (int j = 0; j < 8; j++) ones.u[j] = 0x3F80;  // bf16 1.0

  U8 qf[2];
#pragma unroll
  for (int j = 0; j < 2; j++)
    qf[j].v = *(const bf16x8*)(qk + rowb + (size_t)trow * QKS + qcol + j * 32 + lg * 8);
  asm volatile("s_waitcnt vmcnt(0)" ::: "memory");

  async16(qk + rowb + (size_t)rw * QKS + kcol + c8, Ks[0] + tid * 8);
  async16(qk + rowb + (size_t)(32 + rw) * QKS + kcol + c8, Ks[0] + 2048 + tid * 8);
  async16(vT + (size_t)(vrow0 + rw) * 4096 + bT + c8, Vs[0] + tid * 8);
  async16(vT + (size_t)(vrow0 + 32 + rw) * 4096 + bT + c8, Vs[0] + 2048 + tid * 8);

  f32x4 oa[4] = {};
  f32x4 oas = {};               // lsum accumulator via ones-row MFMA
  float mrun = -1e30f;
  int cur = 0;

  for (int sb = 0; sb <= qt; ++sb) {
    if (sb < qt) {
      const int s1 = (sb + 1) * 64;
      const int nb = cur ^ 1;
      async16(qk + rowb + (size_t)(s1 + rw) * QKS + kcol + c8, Ks[nb] + tid * 8);
      async16(qk + rowb + (size_t)(s1 + 32 + rw) * QKS + kcol + c8, Ks[nb] + 2048 + tid * 8);
      async16(vT + (size_t)(vrow0 + rw) * 4096 + bT + s1 + c8, Vs[nb] + tid * 8);
      async16(vT + (size_t)(vrow0 + 32 + rw) * 4096 + bT + s1 + c8, Vs[nb] + 2048 + tid * 8);
      asm volatile("s_waitcnt vmcnt(4)" ::: "memory");
    } else {
      asm volatile("s_waitcnt vmcnt(0)" ::: "memory");
    }
    block_barrier();

    const unsigned short* Kc = Ks[cur];
    const unsigned short* Vc = Vs[cur];
    const int s0 = sb * 64;

    f32x4 sa[4] = {};
    __builtin_amdgcn_s_setprio(1);
#pragma unroll
    for (int j = 0; j < 2; j++) {
#pragma unroll
      for (int mf = 0; mf < 4; mf++) {
        U8 kf;
        kf.v = *(const bf16x8*)(Kc + (mf * 16 + lr) * 64 + ((j * 32 + lg * 8) ^ swe));
        sa[mf] = __builtin_amdgcn_mfma_f32_16x16x32_bf16(kf.v, qf[j].v, sa[mf], 0, 0, 0);
      }
    }
    __builtin_amdgcn_s_setprio(0);
    float sv[16];
#pragma unroll
    for (int mf = 0; mf < 4; mf++)
#pragma unroll
      for (int r = 0; r < 4; r++) sv[mf * 4 + r] = sa[mf][r];  // log2-scaled

    if (sb == qt) {
#pragma unroll
      for (int mf = 0; mf < 4; mf++)
#pragma unroll
        for (int r = 0; r < 4; r++)
          if (s0 + mf * 16 + lg * 4 + r > trow) sv[mf * 4 + r] = -1e30f;
    }

    // max over 16 (max3-shaped) + 2 cross-lane steps
    const float g0 = fmaxf(fmaxf(sv[0], sv[1]), sv[2]);
    const float g1 = fmaxf(fmaxf(sv[3], sv[4]), sv[5]);
    const float g2 = fmaxf(fmaxf(sv[6], sv[7]), sv[8]);
    const float g3 = fmaxf(fmaxf(sv[9], sv[10]), sv[11]);
    const float g4 = fmaxf(fmaxf(sv[12], sv[13]), sv[14]);
    float tm = fmaxf(fmaxf(fmaxf(fmaxf(g0, g1), g2), fmaxf(g3, g4)), sv[15]);
    tm = fmaxf(tm, __shfl_xor(tm, 16));
    tm = fmaxf(tm, __shfl_xor(tm, 32));

    if (!__all(tm <= mrun + 8.0f)) {  // defer-max (log2 units)
      const float mn = fmaxf(mrun, tm);
      const float corr = __builtin_amdgcn_exp2f(mrun - mn);
#pragma unroll
      for (int c = 0; c < 4; c++)
#pragma unroll
        for (int r = 0; r < 4; r++) oa[c][r] *= corr;
#pragma unroll
      for (int r = 0; r < 4; r++) oas[r] *= corr;
      mrun = mn;
    }

#pragma unroll
    for (int i = 0; i < 16; i++)
      sv[i] = __builtin_amdgcn_exp2f(sv[i] - mrun);

    // P -> LDS, chunk-XOR swizzled (chunk = 8 elems; involution by lr&7)
#pragma unroll
    for (int mf = 0; mf < 4; mf++) {
      ushort4 w;
      w.x = f2bf(sv[mf * 4 + 0]);
      w.y = f2bf(sv[mf * 4 + 1]);
      w.z = f2bf(sv[mf * 4 + 2]);
      w.w = f2bf(sv[mf * 4 + 3]);
      const int wchunk = (mf * 2 + (lg >> 1)) ^ pswz;
      *(ushort4*)&Ps[wave][lr][wchunk * 8 + (lg & 1) * 4] = w;
    }
    asm volatile("" ::: "memory");
    U8 pb[2];
    pb[0].v = *(const bf16x8*)&Ps[wave][lr][(lg ^ pswz) * 8];
    pb[1].v = *(const bf16x8*)&Ps[wave][lr][((4 + lg) ^ pswz) * 8];
    asm volatile("" ::: "memory");

    __builtin_amdgcn_s_setprio(1);
#pragma unroll
    for (int c = 0; c < 4; c++) {
#pragma unroll
      for (int ks = 0; ks < 2; ks++) {
        U8 vf;
        vf.v = *(const bf16x8*)(Vc + (c * 16 + lr) * 64 + ((ks * 32 + lg * 8) ^ swe));
        oa[c] = __builtin_amdgcn_mfma_f32_16x16x32_bf16(vf.v, pb[ks].v, oa[c], 0, 0, 0);
      }
    }
    // lsum contribution: ones-row MFMA (column sums of P)
    oas = __builtin_amdgcn_mfma_f32_16x16x32_bf16(ones.v, pb[0].v, oas, 0, 0, 0);
    oas = __builtin_amdgcn_mfma_f32_16x16x32_bf16(ones.v, pb[1].v, oas, 0, 0, 0);
    __builtin_amdgcn_s_setprio(0);

    block_barrier();
    cur ^= 1;
  }

  const float inv = 1.0f / oas[0];
#pragma unroll
  for (int c = 0; c < 4; c++) {
    ushort4 ov;
    ov.x = f2bf(oa[c][0] * inv);
    ov.y = f2bf(oa[c][1] * inv);
    ov.z = f2bf(oa[c][2] * inv);
    ov.w = f2bf(oa[c][3] * inv);
    *(ushort4*)(o + (size_t)(bT + trow) * C + hh * 64 + c * 16 + lg * 4) = ov;
  }
}

// ---------------------------------------------------------------------------
// Orchestration.  Workspace lifetimes (80 MB):
//   0-6 WqkvT (dead after QKV) | 6-8 WpT (dead after proj) | 8-16 W1T (dead
//   after FFN1) | 16-24 W2T (thru FFN2) | 24-32 h (dead after QKV) |
//   32-48 qkb, 48-56 vTb (dead after attn) | 56-64 att -> h2 |
//   24-56 ff1 after FFN1 | x1 = d_out | FFN2 bf16 partials: 0-16 & 64-80.
// ---------------------------------------------------------------------------
extern "C" void kernel_launch(void* const* d_in, const int* in_sizes, int n_in,
                              void* d_out, int out_size, void* d_ws, size_t ws_size,
                              hipStream_t stream) {
  (void)in_sizes; (void)n_in; (void)out_size; (void)ws_size;
  const int T = 2048, C = 1024, M = 2 * T, C4 = 4 * C;

  const float* x     = (const float*)d_in[0];
  const float* Wq    = (const float*)d_in[1];
  const float* Wk    = (const float*)d_in[2];
  const float* Wv    = (const float*)d_in[3];
  const float* Wproj = (const float*)d_in[4];
  const float* bproj = (const float*)d_in[5];
  const float* W1    = (const float*)d_in[6];
  const float* b1    = (const float*)d_in[7];
  const float* W2    = (const float*)d_in[8];
  const float* b2    = (const float*)d_in[9];
  const float* ln1g  = (const float*)d_in[10];
  const float* ln1b  = (const float*)d_in[11];
  const float* ln2g  = (const float*)d_in[12];
  const float* ln2b  = (const float*)d_in[13];
  float* out = (float*)d_out;

  char* ws = (char*)d_ws;
  const size_t MBy = (size_t)1 << 20;
  unsigned short* WqkvT = (unsigned short*)(ws + 0 * MBy);
  unsigned short* WpT = (unsigned short*)(ws + 6 * MBy);
  unsigned short* W1T = (unsigned short*)(ws + 8 * MBy);
  unsigned short* W2T = (unsigned short*)(ws + 16 * MBy);
  unsigned short* h   = (unsigned short*)(ws + 24 * MBy);
  unsigned short* qkb = (unsigned short*)(ws + 32 * MBy);
  unsigned short* vTb = (unsigned short*)(ws + 48 * MBy);
  unsigned short* att = (unsigned short*)(ws + 56 * MBy);
  float* x1 = out;                                    // x1 lives in d_out
  unsigned short* h2  = att;
  unsigned short* ff1 = h;
  unsigned short* ffP01 = (unsigned short*)(ws + 0 * MBy);   // planes 0,1
  unsigned short* ffP23 = (unsigned short*)(ws + 64 * MBy);  // planes 2,3

  const dim3 tb(32, 8);
  transpose_qkv<<<dim3(2, 32, 48), tb, 0, stream>>>(Wq, Wk, Wv, WqkvT);
  // merged Wproj/W1/W2 transpose: 1024 + 4096 + 4096 = 9216 tiles
  transpose_rest<<<9216, tb, 0, stream>>>(Wproj, W1, W2, WpT, W1T, W2T);

  ln_kernel<<<M, 256, 0, stream>>>(x, ln1g, ln1b, h);

  // Fused QKV (8-phase 256^2): Q cols pre-scaled by 0.125*log2e
  gemm8p<4, 1><<<192, 512, 0, stream>>>(h, WqkvT, qkb, vTb, nullptr, M, 3072, C);

  // attn: 1024 blocks, XCD-grouped + LPT (round-15/17 proven kernel)
  attn_kernel<<<1024, 256, 0, stream>>>(qkb, vTb, att);

  // proj (+bproj +x) -> x1 (d_out)
  gemm_lat2<<<512, 256, 0, stream>>>(att, WpT, x1, bproj, x, M, C, C);

  ln_kernel<<<M, 256, 0, stream>>>(x1, ln2g, ln2b, h2);

  // FFN1 (8-phase 256^2): relu(h2 @ W1 + b1) -> bf16
  gemm8p<2, 1><<<256, 512, 0, stream>>>(h2, W1T, ff1, nullptr, b1, M, C4, C);

  // FFN2: split-K=4 8-phase partials (bf16) + fused reduce (+b2 +x1 in-place)
  gemm8p<5, 4><<<256, 512, 0, stream>>>(ff1, W2T, ffP01, ffP23, nullptr, M, C, C4);
  reduce_add4<<<2048, 256, 0, stream>>>(ffP01, ffP23, b2, out, M * C / 4);
}